// Round 3
// baseline (16887.584 us; speedup 1.0000x reference)
//
#include <hip/hip_runtime.h>
#include <stdint.h>
#include <math.h>

// Problem constants
#define BB   64
#define SS   196
#define BS   12544            // BB*SS
#define NOUT 6422528L         // BS*512

// ---------------- device helpers ----------------
__device__ __forceinline__ float block_red256(float v, float* red, bool ismax) {
#pragma unroll
  for (int o = 32; o > 0; o >>= 1) {
    float t = __shfl_down(v, o, 64);
    v = ismax ? fmaxf(v, t) : v + t;
  }
  int lane = threadIdx.x & 63, wid = threadIdx.x >> 6;
  if (lane == 0) red[wid] = v;
  __syncthreads();
  float r = ismax ? fmaxf(fmaxf(red[0], red[1]), fmaxf(red[2], red[3]))
                  : (red[0] + red[1]) + (red[2] + red[3]);
  __syncthreads();
  return r;
}

// ---------------- GEMM: C[M,N] = A[M,K] @ W[N,K]^T + bias (opt relu) ----------------
__global__ __launch_bounds__(256) void k_gemm_nt(
    const float* __restrict__ A, const float* __restrict__ W,
    const float* __restrict__ bias, float* __restrict__ C,
    int M, int N, int K, int relu) {
  __shared__ float As[16][68];
  __shared__ float Ws[16][68];
  const int tx = threadIdx.x, ty = threadIdx.y;
  const int tid = ty * 16 + tx;
  const int m0 = blockIdx.y * 64, n0 = blockIdx.x * 64;
  const int lr = tid >> 2, lk = (tid & 3) << 2;
  const float* Ap = A + (long)(m0 + lr) * K + lk;
  const float* Wp = W + (long)(n0 + lr) * K + lk;
  float acc[4][4] = {};
  for (int k0 = 0; k0 < K; k0 += 16) {
    float4 av = *(const float4*)(Ap + k0);
    float4 wv = *(const float4*)(Wp + k0);
    As[lk + 0][lr] = av.x; As[lk + 1][lr] = av.y; As[lk + 2][lr] = av.z; As[lk + 3][lr] = av.w;
    Ws[lk + 0][lr] = wv.x; Ws[lk + 1][lr] = wv.y; Ws[lk + 2][lr] = wv.z; Ws[lk + 3][lr] = wv.w;
    __syncthreads();
#pragma unroll
    for (int kk = 0; kk < 16; ++kk) {
      float4 a4 = *(const float4*)&As[kk][ty * 4];
      float4 w4 = *(const float4*)&Ws[kk][tx * 4];
      float a[4] = {a4.x, a4.y, a4.z, a4.w};
      float w[4] = {w4.x, w4.y, w4.z, w4.w};
#pragma unroll
      for (int i = 0; i < 4; ++i)
#pragma unroll
        for (int j = 0; j < 4; ++j) acc[i][j] += a[i] * w[j];
    }
    __syncthreads();
  }
#pragma unroll
  for (int i = 0; i < 4; ++i) {
    int m = m0 + ty * 4 + i;
#pragma unroll
    for (int j = 0; j < 4; ++j) {
      int n = n0 + tx * 4 + j;
      float v = acc[i][j] + bias[n];
      if (relu) v = fmaxf(v, 0.f);
      C[(long)m * N + n] = v;
    }
  }
}

// ---- Embed GEMM: C[b,s,a] = sum_c X[b,c,s]*W[a,c] + bias[a] + pe[s,a] - sub[b,s,a] ----
__global__ __launch_bounds__(256) void k_gemm_embed(
    const float* __restrict__ X,   // [B,1024,196]
    const float* __restrict__ W,   // [512,1024]
    const float* __restrict__ bias,
    const float* __restrict__ wemb, const float* __restrict__ hemb,
    const float* __restrict__ sub,  // nullptr or [BS,512]
    float* __restrict__ C) {        // [BS,512]
  __shared__ float As[16][68];
  __shared__ float Ws[16][68];
  const int tx = threadIdx.x, ty = threadIdx.y;
  const int tid = ty * 16 + tx;
  const int m0 = blockIdx.y * 64, n0 = blockIdx.x * 64;
  const int K = 1024, N = 512;
  const int lr = tid >> 2, lk = (tid & 3) << 2;
  const float* Wp = W + (long)(n0 + lr) * K + lk;
  float acc[4][4] = {};
  for (int k0 = 0; k0 < K; k0 += 16) {
#pragma unroll
    for (int i = 0; i < 4; ++i) {
      int e = tid + i * 256;
      int kk = e >> 6, mm = e & 63;
      int m = m0 + mm;
      int b = m / 196, s = m % 196;
      As[kk][mm] = X[(long)b * 200704 + (long)(k0 + kk) * 196 + s];
    }
    float4 wv = *(const float4*)(Wp + k0);
    Ws[lk + 0][lr] = wv.x; Ws[lk + 1][lr] = wv.y; Ws[lk + 2][lr] = wv.z; Ws[lk + 3][lr] = wv.w;
    __syncthreads();
#pragma unroll
    for (int kk = 0; kk < 16; ++kk) {
      float4 a4 = *(const float4*)&As[kk][ty * 4];
      float4 w4 = *(const float4*)&Ws[kk][tx * 4];
      float a[4] = {a4.x, a4.y, a4.z, a4.w};
      float w[4] = {w4.x, w4.y, w4.z, w4.w};
#pragma unroll
      for (int i = 0; i < 4; ++i)
#pragma unroll
        for (int j = 0; j < 4; ++j) acc[i][j] += a[i] * w[j];
    }
    __syncthreads();
  }
#pragma unroll
  for (int i = 0; i < 4; ++i) {
    int m = m0 + ty * 4 + i;
    int s = m % 196;
#pragma unroll
    for (int j = 0; j < 4; ++j) {
      int n = n0 + tx * 4 + j;
      float pe = (n < 256) ? wemb[(s % 14) * 256 + n] : hemb[(s / 14) * 256 + (n - 256)];
      float v = acc[i][j] + bias[n] + pe;
      if (sub) v -= sub[(long)m * N + n];
      C[(long)m * N + n] = v;
    }
  }
}

// ---- Correlation: C[i,j] += scale * sum_m Za[m,i]*Zb[m,j] (split-K atomic) ----
__global__ __launch_bounds__(256) void k_corr(
    const float* __restrict__ Za, const float* __restrict__ Zb,
    float* __restrict__ C, int mchunk, float scale) {
  __shared__ float As[16][68];
  __shared__ float Bs[16][68];
  const int tx = threadIdx.x, ty = threadIdx.y;
  const int tid = ty * 16 + tx;
  const int i0 = blockIdx.y * 64, j0 = blockIdx.x * 64;
  const int li = (tid & 15) * 4, lm = tid >> 4;
  float acc[4][4] = {};
  const int mstart = blockIdx.z * mchunk;
  for (int m0 = mstart; m0 < mstart + mchunk; m0 += 16) {
    *(float4*)&As[lm][li] = *(const float4*)(Za + (long)(m0 + lm) * 512 + i0 + li);
    *(float4*)&Bs[lm][li] = *(const float4*)(Zb + (long)(m0 + lm) * 512 + j0 + li);
    __syncthreads();
#pragma unroll
    for (int mm = 0; mm < 16; ++mm) {
      float4 a4 = *(const float4*)&As[mm][ty * 4];
      float4 b4 = *(const float4*)&Bs[mm][tx * 4];
      float a[4] = {a4.x, a4.y, a4.z, a4.w};
      float b[4] = {b4.x, b4.y, b4.z, b4.w};
#pragma unroll
      for (int i = 0; i < 4; ++i)
#pragma unroll
        for (int j = 0; j < 4; ++j) acc[i][j] += a[i] * b[j];
    }
    __syncthreads();
  }
#pragma unroll
  for (int i = 0; i < 4; ++i)
#pragma unroll
    for (int j = 0; j < 4; ++j)
      atomicAdd(&C[(long)(i0 + ty * 4 + i) * 512 + j0 + tx * 4 + j], acc[i][j] * scale);
}

// ---- Generic fused-softmax attention, one block per query row. O may alias Q. ----
// QK: wave-cooperative (one wave per key row, coalesced, shuffle-reduce).
// PV: N-loop split into 256/min(D,256) chunks with LDS partial reduce.
__global__ __launch_bounds__(256) void k_attn(
    const float* __restrict__ Q, const float* __restrict__ K, const float* __restrict__ V,
    float* __restrict__ O, int N, int D,
    int64_t qB, int64_t qH, int64_t qR, int64_t kB, int64_t kH, int64_t kR,
    int64_t vB, int64_t vH, int64_t vR, int64_t oB, int64_t oH, int64_t oR,
    float scale, int doClamp) {
  extern __shared__ float sm[];
  float* qs = sm;            // D
  float* p  = sm + D;        // N
  float* po = sm + D + N;    // 256 partials (PV chunked reduce)
  __shared__ float red[4];
  const int m = blockIdx.x, h = blockIdx.y, b = blockIdx.z;
  const float* q  = Q + b * qB + h * qH + m * qR;
  const float* Kb = K + b * kB + h * kH;
  const float* Vb = V + b * vB + h * vH;
  float* o = O + b * oB + h * oH + m * oR;
  const int t = threadIdx.x;
  const int lane = t & 63, wid = t >> 6;
  for (int i = t; i < D; i += 256) qs[i] = q[i];
  __syncthreads();
  // ---- phase 1: scores, one wave per key row ----
  for (int n = wid; n < N; n += 4) {
    const float* kr = Kb + (long)n * kR;
    float s = 0.f;
#pragma unroll 8
    for (int d = lane; d < D; d += 64) s += qs[d] * kr[d];
#pragma unroll
    for (int off = 32; off > 0; off >>= 1) s += __shfl_down(s, off, 64);
    if (lane == 0) {
      s *= scale;
      if (doClamp) s = fminf(fmaxf(s, -100.f), 100.f);
      p[n] = s;
    }
  }
  __syncthreads();
  // ---- phase 2: softmax over p[0..N) ----
  float mx = -1e30f;
  for (int n = t; n < N; n += 256) mx = fmaxf(mx, p[n]);
  mx = block_red256(mx, red, true);
  float sum = 0.f;
  for (int n = t; n < N; n += 256) {
    float e = expf(p[n] - mx);
    p[n] = e;
    sum += e;
  }
  sum = block_red256(sum, red, false);
  float inv = 1.0f / sum;
  // ---- phase 3: PV, chunked over N for small D ----
  const int dth = (D < 256) ? D : 256;
  const int nch = 256 / dth;           // 1 (D>=256) or 4 (D=64)
  const int c = t / dth, d0 = t % dth;
  const int nper = (N + nch - 1) / nch;
  const int ns = c * nper;
  const int ne = (ns + nper < N) ? ns + nper : N;
  for (int d = d0; d < D; d += dth) {
    float acc = 0.f;
    int n = ns;
    for (; n + 4 <= ne; n += 4) {
      float v0 = Vb[(long)(n + 0) * vR + d];
      float v1 = Vb[(long)(n + 1) * vR + d];
      float v2 = Vb[(long)(n + 2) * vR + d];
      float v3 = Vb[(long)(n + 3) * vR + d];
      acc += p[n] * v0 + p[n + 1] * v1 + p[n + 2] * v2 + p[n + 3] * v3;
    }
    for (; n < ne; ++n) acc += p[n] * Vb[(long)n * vR + d];
    if (nch == 1) o[d] = acc * inv;
    else po[c * dth + d] = acc;
  }
  if (nch > 1) {
    __syncthreads();
    if (t < D) {
      float acc = 0.f;
#pragma unroll 4
      for (int cc = 0; cc < nch; ++cc) acc += po[cc * dth + t];
      o[t] = acc * inv;
    }
  }
}

// ---- Residual + LayerNorm (in place into h) ----
__global__ __launch_bounds__(256) void k_addln(
    float* __restrict__ h, const float* __restrict__ o,
    const float* __restrict__ g, const float* __restrict__ be) {
  __shared__ float red[4];
  long row = blockIdx.x;
  float* hr = h + row * 512;
  const float* orow = o + row * 512;
  int t = threadIdx.x;
  float v0 = hr[t] + orow[t];
  float v1 = hr[t + 256] + orow[t + 256];
  float mean = block_red256(v0 + v1, red, false) * (1.0f / 512.0f);
  float d0 = v0 - mean, d1 = v1 - mean;
  float var = block_red256(d0 * d0 + d1 * d1, red, false) * (1.0f / 512.0f);
  float inv = 1.0f / sqrtf(var + 1e-5f);
  hr[t] = d0 * inv * g[t] + be[t];
  hr[t + 256] = d1 * inv * g[t + 256] + be[t + 256];
}

// ---- small utility kernels ----
__global__ void k_zero(float* __restrict__ p, int n) {
  int i = blockIdx.x * 256 + threadIdx.x;
  if (i < n) p[i] = 0.f;
}

__global__ __launch_bounds__(256) void k_colstats(
    const float* __restrict__ f, float* __restrict__ sums, float* __restrict__ sqs) {
  int c = blockIdx.x * 32 + (threadIdx.x & 31);
  int rbase = blockIdx.y * 256;
  int r0 = rbase + (threadIdx.x >> 5);
  float s = 0.f, s2 = 0.f;
  for (int r = r0; r < rbase + 256; r += 8) {
    float v = f[(long)r * 512 + c];
    s += v; s2 += v * v;
  }
  __shared__ float sh[256], sh2[256];
  sh[threadIdx.x] = s; sh2[threadIdx.x] = s2;
  __syncthreads();
  if (threadIdx.x < 32) {
    for (int i = 1; i < 8; ++i) { s += sh[i * 32 + threadIdx.x]; s2 += sh2[i * 32 + threadIdx.x]; }
    atomicAdd(&sums[c], s);
    atomicAdd(&sqs[c], s2);
  }
}

__global__ void k_finstats(const float* __restrict__ sums, const float* __restrict__ sqs,
                           float* __restrict__ mean, float* __restrict__ istd) {
  int c = blockIdx.x * 256 + threadIdx.x;
  float mu = sums[c] / 12544.0f;
  float var = (sqs[c] - 12544.0f * mu * mu) / 12543.0f;
  mean[c] = mu;
  istd[c] = 1.0f / sqrtf(var);
}

__global__ __launch_bounds__(256) void k_znorm(float* __restrict__ f, const float* __restrict__ mean,
                                               const float* __restrict__ istd) {
  long i = (long)blockIdx.x * 256 + threadIdx.x;
  int c = (int)(i & 511);
  f[i] = (f[i] - mean[c]) * istd[c];
}

__global__ __launch_bounds__(256) void k_cdcr(const float* __restrict__ Cm, float* __restrict__ out) {
  __shared__ double s_on[256], s_off[256];
  double on = 0, off = 0;
  for (int i = threadIdx.x; i < 262144; i += 256) {
    float v = Cm[i];
    int r = i >> 9, c = i & 511;
    if (r == c) { double d = (double)v - 1.0; on += d * d; }
    else        { off += (double)v * (double)v; }
  }
  s_on[threadIdx.x] = on; s_off[threadIdx.x] = off;
  __syncthreads();
  for (int st = 128; st > 0; st >>= 1) {
    if (threadIdx.x < st) { s_on[threadIdx.x] += s_on[threadIdx.x + st]; s_off[threadIdx.x] += s_off[threadIdx.x + st]; }
    __syncthreads();
  }
  if (threadIdx.x == 0) out[0] = (float)(s_on[0] + 0.003 * s_off[0]);
}

__global__ __launch_bounds__(64) void k_mask(const float* __restrict__ capo, float* __restrict__ mask) {
  int pidx = blockIdx.x;
  float s = 0.f;
  for (int i = threadIdx.x; i < 512; i += 64) s += capo[(long)pidx * 512 + i];
#pragma unroll
  for (int o = 32; o > 0; o >>= 1) s += __shfl_down(s, o, 64);
  if (threadIdx.x == 0) mask[pidx] = (s != 0.f) ? 1.f : 0.f;
}

__global__ __launch_bounds__(256) void k_meannc(const float* __restrict__ src, const float* __restrict__ mask,
                                                float* __restrict__ vec) {
  int d = blockIdx.x * 256 + threadIdx.x;
  int b = blockIdx.y;
  float acc = 0.f, ms = 0.f;
  for (int nc = 0; nc < 16; ++nc) {
    float mk = mask ? mask[b * 16 + nc] : 1.f;
    acc += src[((long)b * 16 + nc) * 512 + d] * mk;
    ms += mk;
  }
  vec[(long)b * 512 + d] = acc / fmaxf(ms, 1e-6f);
}

__global__ __launch_bounds__(256) void k_mse(const float* __restrict__ full, const float* __restrict__ vec,
                                             double* __restrict__ part) {
  double loc = 0;
  const long n = NOUT;
  for (long i = (long)blockIdx.x * 256 + threadIdx.x; i < n; i += 256L * 1024) {
    int d = (int)(i & 511);
    int b = (int)(i >> 9) / 196;
    float df = full[i] - vec[b * 512 + d];
    loc += (double)df * (double)df;
  }
  __shared__ double sh[256];
  sh[threadIdx.x] = loc;
  __syncthreads();
  for (int st = 128; st > 0; st >>= 1) {
    if (threadIdx.x < st) sh[threadIdx.x] += sh[threadIdx.x + st];
    __syncthreads();
  }
  if (threadIdx.x == 0) part[blockIdx.x] = sh[0];
}

__global__ void k_finloss(const double* __restrict__ part, float* __restrict__ out) {
  __shared__ double sh[256];
  double s = 0;
  for (int i = threadIdx.x; i < 4096; i += 256) s += part[i];
  sh[threadIdx.x] = s;
  __syncthreads();
  for (int st = 128; st > 0; st >>= 1) {
    if (threadIdx.x < st) sh[threadIdx.x] += sh[threadIdx.x + st];
    __syncthreads();
  }
  if (threadIdx.x == 0) out[0] = (float)(sh[0] / (64.0 * 196.0 * 512.0));
}

__global__ __launch_bounds__(256) void k_concat2(float* __restrict__ dst, const float* __restrict__ a,
                                                 const float* __restrict__ b) {
  int i = blockIdx.x * 256 + threadIdx.x;   // 64*1024
  int col = i & 1023, row = i >> 10;
  dst[i] = (col < 512) ? a[row * 512 + col] : b[row * 512 + col - 512];
}

// comb chunk: rows [r0, r0+3136) of [BS,2048] into dst
__global__ __launch_bounds__(256) void k_comb_chunk(
    float* __restrict__ dst, const float* __restrict__ d1, const float* __restrict__ d2,
    const float* __restrict__ txt, const float* __restrict__ al, long r0) {
  long i = (long)blockIdx.x * 256 + threadIdx.x;  // 3136*2048
  int col = (int)(i & 2047);
  long m = r0 + (i >> 11);
  int b = (int)(m / 196);
  float v;
  if (col < 512)       v = d1[m * 512 + col];
  else if (col < 1024) v = d2[m * 512 + col - 512];
  else if (col < 1536) v = txt[(long)b * 512 + col - 1024];
  else                 v = al[(long)b * 512 + col - 1536];
  dst[i] = v;
}

// ---------------- host ----------------
extern "C" void kernel_launch(void* const* d_in, const int* in_sizes, int n_in,
                              void* d_out, int out_size, void* d_ws, size_t ws_size,
                              hipStream_t stream) {
  (void)in_sizes; (void)n_in; (void)out_size; (void)ws_size;
  const float* in1    = (const float*)d_in[0];
  const float* in2    = (const float*)d_in[1];
  const float* cap1   = (const float*)d_in[2];
  const float* cap2   = (const float*)d_in[3];
  const float* imgw   = (const float*)d_in[4];
  const float* imgb   = (const float*)d_in[5];
  const float* wemb   = (const float*)d_in[6];
  const float* hemb   = (const float*)d_in[7];
  const float* mlpw1  = (const float*)d_in[8];
  const float* mlpb1  = (const float*)d_in[9];
  const float* mlpw2  = (const float*)d_in[10];
  const float* mlpb2  = (const float*)d_in[11];
  const float* fcw    = (const float*)d_in[12];
  const float* fcb    = (const float*)d_in[13];
  const float* efcw   = (const float*)d_in[14];
  const float* efcb   = (const float*)d_in[15];
  const float* efc2w  = (const float*)d_in[16];
  const float* efc2b  = (const float*)d_in[17];
  const float* trinw  = (const float*)d_in[18];
  const float* trinb  = (const float*)d_in[19];
  const float* troutw = (const float*)d_in[20];
  const float* troutb = (const float*)d_in[21];
  const float* trlng  = (const float*)d_in[22];
  const float* trlnb  = (const float*)d_in[23];
  const float* itqw = (const float*)d_in[24]; const float* itqb = (const float*)d_in[25];
  const float* itkw = (const float*)d_in[26]; const float* itkb = (const float*)d_in[27];
  const float* itvw = (const float*)d_in[28]; const float* itvb = (const float*)d_in[29];
  const float* caqw = (const float*)d_in[30]; const float* caqb = (const float*)d_in[31];
  const float* cakw = (const float*)d_in[32]; const float* cakb = (const float*)d_in[33];
  const float* cavw = (const float*)d_in[34]; const float* cavb = (const float*)d_in[35];
  const float* saqw = (const float*)d_in[36]; const float* saqb = (const float*)d_in[37];
  const float* sakw = (const float*)d_in[38]; const float* sakb = (const float*)d_in[39];
  const float* savw = (const float*)d_in[40]; const float* savb = (const float*)d_in[41];

  float* out = (float*)d_out;

  // ---- workspace carve (~166 MB total) ----
  const size_t SZ = (size_t)BS * 512;        // 6,422,528 floats (24.5 MB)
  float* w = (float*)d_ws;
  auto alloc = [&](size_t n) { float* p = w; w += n; return p; };
  float* h1 = alloc(SZ);
  float* h2 = alloc(SZ);
  float* tA = alloc(SZ);
  float* tB = alloc(SZ);
  float* tC = alloc(SZ);
  float* tD = alloc(SZ);
  float* cap1o = alloc(64 * 16 * 512);
  float* cap2o = alloc(64 * 16 * 512);
  float* qc1   = alloc(64 * 16 * 512);
  float* qc2   = alloc(64 * 16 * 512);
  float* attb  = alloc(64 * 16 * 512);
  float* cmat  = alloc(512 * 512);
  float* colsum1 = alloc(512); float* colsq1 = alloc(512);
  float* colsum2 = alloc(512); float* colsq2 = alloc(512);
  float* mean1 = alloc(512); float* istd1 = alloc(512);
  float* mean2 = alloc(512); float* istd2 = alloc(512);
  float* mask1 = alloc(1024); float* mask2 = alloc(1024);
  float* vdbef = alloc(64 * 512); float* vdaft = alloc(64 * 512);
  float* vsbef = alloc(64 * 512); float* vsaft = alloc(64 * 512);
  float* cm1 = alloc(64 * 512); float* cm2 = alloc(64 * 512);
  float* vdyn = alloc(64 * 512); float* vsta = alloc(64 * 512);
  float* valign = alloc(64 * 512); float* vtxt = alloc(64 * 512);
  float* ccat = alloc(64 * 1024);
  double* msepart = (double*)alloc(4096 * 2);  // 4096 doubles

  auto gemm = [&](const float* Aa, const float* Ww, const float* bb, float* Cc,
                  int M, int N, int K, int relu) {
    k_gemm_nt<<<dim3(N / 64, M / 64), dim3(16, 16), 0, stream>>>(Aa, Ww, bb, Cc, M, N, K, relu);
  };
  auto attn = [&](const float* Qp, const float* Kp, const float* Vp, float* Op,
                  int M, int H, int N, int D,
                  int64_t qB, int64_t qH, int64_t qR,
                  int64_t kB, int64_t kH, int64_t kR,
                  int64_t vB, int64_t vH, int64_t vR,
                  int64_t oB, int64_t oH, int64_t oR,
                  float scale, int clampf) {
    size_t smem = (size_t)(D + N + 256) * sizeof(float);
    k_attn<<<dim3(M, H, BB), 256, smem, stream>>>(Qp, Kp, Vp, Op, N, D,
        qB, qH, qR, kB, kH, kR, vB, vH, vR, oB, oH, oR, scale, clampf);
  };
  auto embed = [&](const float* X, const float* sub, float* Cc) {
    k_gemm_embed<<<dim3(8, BS / 64), dim3(16, 16), 0, stream>>>(X, imgw, imgb, wemb, hemb, sub, Cc);
  };

  const float scalE = 1.0f / sqrtf(512.0f);
  const int64_t RB = (int64_t)SS * 512;  // 100352
  const int64_t QB = 16 * 512;           // 8192

  // ---- Phase 1: embed (h starts as x) + caption projections ----
  embed(in1, nullptr, h1);
  embed(in2, nullptr, h2);
  gemm(cap1, fcw, fcb, cap1o, 1024, 512, 768, 0);
  gemm(cap2, fcw, fcb, cap2o, 1024, 512, 768, 0);
  k_meannc<<<dim3(2, 64), 256, 0, stream>>>(cap1o, nullptr, cm1);
  k_meannc<<<dim3(2, 64), 256, 0, stream>>>(cap2o, nullptr, cm2);

  // ---- Phase 2: CDCR loss (f1->tA, f2->tB, hidden chunk in tC) ----
  for (int c = 0; c < 4; ++c) {
    const size_t off = (size_t)c * 3136 * 512;
    gemm(h1 + off, mlpw1, mlpb1, tC, 3136, 2048, 512, 1);
    gemm(tC, mlpw2, mlpb2, tA + off, 3136, 512, 2048, 0);
  }
  for (int c = 0; c < 4; ++c) {
    const size_t off = (size_t)c * 3136 * 512;
    gemm(h2 + off, mlpw1, mlpb1, tC, 3136, 2048, 512, 1);
    gemm(tC, mlpw2, mlpb2, tB + off, 3136, 512, 2048, 0);
  }
  k_zero<<<8, 256, 0, stream>>>(colsum1, 2048);  // colsum1..colsq2 contiguous
  k_colstats<<<dim3(16, 49), 256, 0, stream>>>(tA, colsum1, colsq1);
  k_colstats<<<dim3(16, 49), 256, 0, stream>>>(tB, colsum2, colsq2);
  k_finstats<<<2, 256, 0, stream>>>(colsum1, colsq1, mean1, istd1);
  k_finstats<<<2, 256, 0, stream>>>(colsum2, colsq2, mean2, istd2);
  k_znorm<<<25088, 256, 0, stream>>>(tA, mean1, istd1);
  k_znorm<<<25088, 256, 0, stream>>>(tB, mean2, istd2);
  k_zero<<<1024, 256, 0, stream>>>(cmat, 262144);
  k_corr<<<dim3(8, 8, 8), dim3(16, 16), 0, stream>>>(tA, tB, cmat, BS / 8, 1.0f / (float)BS);
  k_cdcr<<<1, 256, 0, stream>>>(cmat, out + NOUT);

  // ---- Phase 3: cross-transformer (2 layers, simultaneous update) ----
  for (int l = 0; l < 2; ++l) {
    const float* Wq = trinw + (size_t)l * 1536 * 512;
    const float* Wk = Wq + 512 * 512;
    const float* Wv = Wq + 2 * 512 * 512;
    const float* bq = trinb + l * 1536;
    const float* bk = bq + 512;
    const float* bv = bq + 1024;
    const float* Wo = troutw + (size_t)l * 512 * 512;
    const float* bo = troutb + l * 512;
    const float* g  = trlng + l * 512;
    const float* be = trlnb + l * 512;
    // dir1: q=h1, kv=h2
    gemm(h1, Wq, bq, tA, BS, 512, 512, 0);
    gemm(h2, Wk, bk, tB, BS, 512, 512, 0);
    gemm(h2, Wv, bv, tC, BS, 512, 512, 0);
    attn(tA, tB, tC, tA, SS, 8, SS, 64, RB, 64, 512, RB, 64, 512, RB, 64, 512, RB, 64, 512, 0.125f, 0);
    gemm(tA, Wo, bo, tD, BS, 512, 512, 0);       // o1 -> tD
    // dir2 projections from ORIGINAL h1,h2
    gemm(h2, Wq, bq, tA, BS, 512, 512, 0);
    gemm(h1, Wk, bk, tB, BS, 512, 512, 0);
    gemm(h1, Wv, bv, tC, BS, 512, 512, 0);
    k_addln<<<BS, 256, 0, stream>>>(h1, tD, g, be);  // h1 consumed above; update now
    attn(tA, tB, tC, tA, SS, 8, SS, 64, RB, 64, 512, RB, 64, 512, RB, 64, 512, RB, 64, 512, 0.125f, 0);
    gemm(tA, Wo, bo, tD, BS, 512, 512, 0);       // o2 -> tD
    k_addln<<<BS, 256, 0, stream>>>(h2, tD, g, be);
  }

  // ---- Phase 4: diffs via embed recompute (deterministic, bitwise-equal x) ----
  embed(in1, h1, tC);   // diff1 = x1 - h1
  embed(in2, h2, tD);   // diff2 = x2 - h2
  // h1, h2 now free

  // ---- Phase 5: ITDA (queries constant over S -> per-(b,nc) attention + masked mean) ----
  gemm(cap1o, itqw, itqb, qc1, 1024, 512, 512, 0);
  gemm(cap2o, itqw, itqb, qc2, 1024, 512, 512, 0);
  k_mask<<<1024, 64, 0, stream>>>(cap1o, mask1);
  k_mask<<<1024, 64, 0, stream>>>(cap2o, mask2);
  // K1,V1 from diff1
  gemm(tC, itkw, itkb, tA, BS, 512, 512, 0);
  gemm(tC, itvw, itvb, tB, BS, 512, 512, 0);
  attn(qc2, tA, tB, attb, 16, 1, SS, 512, QB, 0, 512, RB, 0, 512, RB, 0, 512, QB, 0, 512, scalE, 1);
  k_meannc<<<dim3(2, 64), 256, 0, stream>>>(attb, mask2, vdbef);   // d_bef
  attn(qc1, tA, tB, attb, 16, 1, SS, 512, QB, 0, 512, RB, 0, 512, RB, 0, 512, QB, 0, 512, scalE, 1);
  k_meannc<<<dim3(2, 64), 256, 0, stream>>>(attb, mask1, vsbef);   // s_bef
  // K2,V2 from diff2
  gemm(tD, itkw, itkb, tA, BS, 512, 512, 0);
  gemm(tD, itvw, itvb, tB, BS, 512, 512, 0);
  attn(qc1, tA, tB, attb, 16, 1, SS, 512, QB, 0, 512, RB, 0, 512, RB, 0, 512, QB, 0, 512, scalE, 1);
  k_meannc<<<dim3(2, 64), 256, 0, stream>>>(attb, mask1, vdaft);   // d_aft
  attn(qc2, tA, tB, attb, 16, 1, SS, 512, QB, 0, 512, RB, 0, 512, RB, 0, 512, QB, 0, 512, scalE, 1);
  k_meannc<<<dim3(2, 64), 256, 0, stream>>>(attb, mask2, vsaft);   // s_aft

  // ---- Phase 6: ECA x4 with immediate MSE vs ITDA vector ----
  auto eca_mse = [&](const float* xq, const float* xkv,
                     const float* qw2, const float* qb2, const float* kw2, const float* kb2,
                     const float* vw2, const float* vb2, const float* vec, double* part) {
    gemm(xq,  qw2, qb2, tA, BS, 512, 512, 0);
    gemm(xkv, kw2, kb2, tB, BS, 512, 512, 0);
    gemm(xkv, vw2, vb2, h1, BS, 512, 512, 0);
    attn(tA, tB, h1, tA, SS, 1, SS, 512, RB, 0, 512, RB, 0, 512, RB, 0, 512, RB, 0, 512, scalE, 1);
    k_mse<<<1024, 256, 0, stream>>>(tA, vec, part);
  };
  eca_mse(tC, tD, caqw, caqb, cakw, cakb, cavw, cavb, vdbef, msepart);          // c12 vs d_bef
  eca_mse(tD, tC, caqw, caqb, cakw, cakb, cavw, cavb, vdaft, msepart + 1024);   // c21 vs d_aft
  eca_mse(tC, tC, saqw, saqb, sakw, sakb, savw, savb, vsbef, msepart + 2048);   // s11 vs s_bef
  eca_mse(tD, tD, saqw, saqb, sakw, sakb, savw, savb, vsaft, msepart + 3072);   // s22 vs s_aft
  k_finloss<<<1, 256, 0, stream>>>(msepart, out + NOUT + 1);

  // ---- Phase 7: efc chain (per-batch vectors) ----
  k_concat2<<<256, 256, 0, stream>>>(ccat, vdbef, vdaft);
  gemm(ccat, efcw, efcb, vdyn, 64, 512, 1024, 1);
  k_concat2<<<256, 256, 0, stream>>>(ccat, vsbef, vsaft);
  gemm(ccat, efcw, efcb, vsta, 64, 512, 1024, 1);
  k_concat2<<<256, 256, 0, stream>>>(ccat, vdyn, vsta);
  gemm(ccat, efcw, efcb, valign, 64, 512, 1024, 1);
  k_concat2<<<256, 256, 0, stream>>>(ccat, cm1, cm2);
  gemm(ccat, efcw, efcb, vtxt, 64, 512, 1024, 1);

  // ---- Phase 8: final projection, chunked comb (3136 rows/chunk) ----
  for (int c = 0; c < 4; ++c) {
    long r0 = (long)c * 3136;
    k_comb_chunk<<<25088, 256, 0, stream>>>(tA, tC, tD, vtxt, valign, r0);
    gemm(tA, efc2w, efc2b, out + r0 * 512, 3136, 512, 2048, 1);
  }
}

// Round 4
// 15552.333 us; speedup vs baseline: 1.0859x; 1.0859x over previous
//
#include <hip/hip_runtime.h>
#include <stdint.h>
#include <math.h>

// Problem constants
#define BB   64
#define SS   196
#define BS   12544            // BB*SS
#define NOUT 6422528L         // BS*512

// ---------------- device helpers ----------------
__device__ __forceinline__ float block_red256(float v, float* red, bool ismax) {
#pragma unroll
  for (int o = 32; o > 0; o >>= 1) {
    float t = __shfl_down(v, o, 64);
    v = ismax ? fmaxf(v, t) : v + t;
  }
  int lane = threadIdx.x & 63, wid = threadIdx.x >> 6;
  if (lane == 0) red[wid] = v;
  __syncthreads();
  float r = ismax ? fmaxf(fmaxf(red[0], red[1]), fmaxf(red[2], red[3]))
                  : (red[0] + red[1]) + (red[2] + red[3]);
  __syncthreads();
  return r;
}

// ---------------- GEMM: C[M,N] = A[M,K] @ W[N,K]^T + bias (opt relu) ----------------
__global__ __launch_bounds__(256) void k_gemm_nt(
    const float* __restrict__ A, const float* __restrict__ W,
    const float* __restrict__ bias, float* __restrict__ C,
    int M, int N, int K, int relu) {
  __shared__ float As[16][68];
  __shared__ float Ws[16][68];
  const int tx = threadIdx.x, ty = threadIdx.y;
  const int tid = ty * 16 + tx;
  const int m0 = blockIdx.y * 64, n0 = blockIdx.x * 64;
  const int lr = tid >> 2, lk = (tid & 3) << 2;
  const float* Ap = A + (long)(m0 + lr) * K + lk;
  const float* Wp = W + (long)(n0 + lr) * K + lk;
  float acc[4][4] = {};
  for (int k0 = 0; k0 < K; k0 += 16) {
    float4 av = *(const float4*)(Ap + k0);
    float4 wv = *(const float4*)(Wp + k0);
    As[lk + 0][lr] = av.x; As[lk + 1][lr] = av.y; As[lk + 2][lr] = av.z; As[lk + 3][lr] = av.w;
    Ws[lk + 0][lr] = wv.x; Ws[lk + 1][lr] = wv.y; Ws[lk + 2][lr] = wv.z; Ws[lk + 3][lr] = wv.w;
    __syncthreads();
#pragma unroll
    for (int kk = 0; kk < 16; ++kk) {
      float4 a4 = *(const float4*)&As[kk][ty * 4];
      float4 w4 = *(const float4*)&Ws[kk][tx * 4];
      float a[4] = {a4.x, a4.y, a4.z, a4.w};
      float w[4] = {w4.x, w4.y, w4.z, w4.w};
#pragma unroll
      for (int i = 0; i < 4; ++i)
#pragma unroll
        for (int j = 0; j < 4; ++j) acc[i][j] += a[i] * w[j];
    }
    __syncthreads();
  }
#pragma unroll
  for (int i = 0; i < 4; ++i) {
    int m = m0 + ty * 4 + i;
#pragma unroll
    for (int j = 0; j < 4; ++j) {
      int n = n0 + tx * 4 + j;
      float v = acc[i][j] + bias[n];
      if (relu) v = fmaxf(v, 0.f);
      C[(long)m * N + n] = v;
    }
  }
}

// ---- Batched NT GEMM: C[z][m,n] = scale * sum_k A[z][m,k]*B[z][n,k], opt clamp ----
// z = z1*nz2 + z2 for dual batch strides. M,N bounds-checked (row clamp for loads).
__global__ __launch_bounds__(256) void k_bgemm_nt(
    const float* __restrict__ A, const float* __restrict__ B, float* __restrict__ C,
    int M, int N, int K, int lda, int ldb, int ldc, int nz2,
    int64_t sA1, int64_t sA2, int64_t sB1, int64_t sB2, int64_t sC1, int64_t sC2,
    float scale, int clampf) {
  __shared__ float As[16][68];
  __shared__ float Bs[16][68];
  const int tx = threadIdx.x, ty = threadIdx.y;
  const int tid = ty * 16 + tx;
  const int m0 = blockIdx.y * 64, n0 = blockIdx.x * 64;
  const int z = blockIdx.z;
  const int z1 = z / nz2, z2 = z % nz2;
  const float* Ab = A + z1 * sA1 + z2 * sA2;
  const float* Bb = B + z1 * sB1 + z2 * sB2;
  float* Cb = C + z1 * sC1 + z2 * sC2;
  const int lr = tid >> 2, lk = (tid & 3) << 2;
  const int ar = (m0 + lr < M) ? m0 + lr : M - 1;
  const int br = (n0 + lr < N) ? n0 + lr : N - 1;
  const float* Ap = Ab + (long)ar * lda + lk;
  const float* Bp = Bb + (long)br * ldb + lk;
  float acc[4][4] = {};
  for (int k0 = 0; k0 < K; k0 += 16) {
    float4 av = *(const float4*)(Ap + k0);
    float4 bv = *(const float4*)(Bp + k0);
    As[lk + 0][lr] = av.x; As[lk + 1][lr] = av.y; As[lk + 2][lr] = av.z; As[lk + 3][lr] = av.w;
    Bs[lk + 0][lr] = bv.x; Bs[lk + 1][lr] = bv.y; Bs[lk + 2][lr] = bv.z; Bs[lk + 3][lr] = bv.w;
    __syncthreads();
#pragma unroll
    for (int kk = 0; kk < 16; ++kk) {
      float4 a4 = *(const float4*)&As[kk][ty * 4];
      float4 b4 = *(const float4*)&Bs[kk][tx * 4];
      float a[4] = {a4.x, a4.y, a4.z, a4.w};
      float b[4] = {b4.x, b4.y, b4.z, b4.w};
#pragma unroll
      for (int i = 0; i < 4; ++i)
#pragma unroll
        for (int j = 0; j < 4; ++j) acc[i][j] += a[i] * b[j];
    }
    __syncthreads();
  }
#pragma unroll
  for (int i = 0; i < 4; ++i) {
    int m = m0 + ty * 4 + i;
    if (m >= M) continue;
#pragma unroll
    for (int j = 0; j < 4; ++j) {
      int n = n0 + tx * 4 + j;
      if (n >= N) continue;
      float v = acc[i][j] * scale;
      if (clampf) v = fminf(fmaxf(v, -100.f), 100.f);
      Cb[(long)m * ldc + n] = v;
    }
  }
}

// ---- Batched NN GEMM: C[z][m,n] = sum_k A[z][m,k]*B[z][k,n]. K mult of 16;
// B k-rows clamped to KBvalid-1 (A pad cols are zero so product is exact). ----
__global__ __launch_bounds__(256) void k_bgemm_nn(
    const float* __restrict__ A, const float* __restrict__ B, float* __restrict__ C,
    int M, int N, int K, int KBvalid, int lda, int ldb, int ldc, int nz2,
    int64_t sA1, int64_t sA2, int64_t sB1, int64_t sB2, int64_t sC1, int64_t sC2) {
  __shared__ float As[16][68];
  __shared__ float Bs[16][68];
  const int tx = threadIdx.x, ty = threadIdx.y;
  const int tid = ty * 16 + tx;
  const int m0 = blockIdx.y * 64, n0 = blockIdx.x * 64;
  const int z = blockIdx.z;
  const int z1 = z / nz2, z2 = z % nz2;
  const float* Ab = A + z1 * sA1 + z2 * sA2;
  const float* Bb = B + z1 * sB1 + z2 * sB2;
  float* Cb = C + z1 * sC1 + z2 * sC2;
  const int lr = tid >> 2, lk = (tid & 3) << 2;
  const int ar = (m0 + lr < M) ? m0 + lr : M - 1;
  const float* Ap = Ab + (long)ar * lda + lk;
  const int bk = tid >> 6, bn = tid & 63;   // B staging: 4 k-rows x 64 n-cols
  float acc[4][4] = {};
  for (int k0 = 0; k0 < K; k0 += 16) {
    float4 av = *(const float4*)(Ap + k0);
    As[lk + 0][lr] = av.x; As[lk + 1][lr] = av.y; As[lk + 2][lr] = av.z; As[lk + 3][lr] = av.w;
#pragma unroll
    for (int kko = 0; kko < 16; kko += 4) {
      int k = k0 + bk + kko;
      int kc = (k < KBvalid) ? k : KBvalid - 1;
      Bs[bk + kko][bn] = Bb[(long)kc * ldb + n0 + bn];
    }
    __syncthreads();
#pragma unroll
    for (int kk = 0; kk < 16; ++kk) {
      float4 a4 = *(const float4*)&As[kk][ty * 4];
      float4 b4 = *(const float4*)&Bs[kk][tx * 4];
      float a[4] = {a4.x, a4.y, a4.z, a4.w};
      float b[4] = {b4.x, b4.y, b4.z, b4.w};
#pragma unroll
      for (int i = 0; i < 4; ++i)
#pragma unroll
        for (int j = 0; j < 4; ++j) acc[i][j] += a[i] * b[j];
    }
    __syncthreads();
  }
#pragma unroll
  for (int i = 0; i < 4; ++i) {
    int m = m0 + ty * 4 + i;
    if (m >= M) continue;
#pragma unroll
    for (int j = 0; j < 4; ++j) {
      int n = n0 + tx * 4 + j;
      if (n >= N) continue;
      Cb[(long)m * ldc + n] = acc[i][j];
    }
  }
}

// ---- Row softmax over S rows of width 196, ld=208; zeroes pad cols. 1 wave/row. ----
__global__ __launch_bounds__(256) void k_softmax_rows(float* __restrict__ S, int nrows) {
  int row = blockIdx.x * 4 + (threadIdx.x >> 6);
  int lane = threadIdx.x & 63;
  if (row >= nrows) return;
  float* p = S + (long)row * 208;
  float v0 = p[lane];
  float v1 = p[lane + 64];
  float v2 = p[lane + 128];
  float v3 = (lane + 192 < 196) ? p[lane + 192] : -1e30f;
  float mx = fmaxf(fmaxf(v0, v1), fmaxf(v2, v3));
#pragma unroll
  for (int o = 32; o > 0; o >>= 1) mx = fmaxf(mx, __shfl_down(mx, o, 64));
  mx = __shfl(mx, 0, 64);
  float e0 = expf(v0 - mx), e1 = expf(v1 - mx), e2 = expf(v2 - mx);
  float e3 = (lane + 192 < 196) ? expf(v3 - mx) : 0.f;
  float s = e0 + e1 + e2 + e3;
#pragma unroll
  for (int o = 32; o > 0; o >>= 1) s += __shfl_down(s, o, 64);
  s = __shfl(s, 0, 64);
  float inv = 1.0f / s;
  p[lane] = e0 * inv;
  p[lane + 64] = e1 * inv;
  p[lane + 128] = e2 * inv;
  if (lane + 192 < 208) p[lane + 192] = (lane + 192 < 196) ? e3 * inv : 0.f;
}

// ---- Embed GEMM: C[b,s,a] = sum_c X[b,c,s]*W[a,c] + bias[a] + pe[s,a] - sub[b,s,a] ----
__global__ __launch_bounds__(256) void k_gemm_embed(
    const float* __restrict__ X,   // [B,1024,196]
    const float* __restrict__ W,   // [512,1024]
    const float* __restrict__ bias,
    const float* __restrict__ wemb, const float* __restrict__ hemb,
    const float* __restrict__ sub,  // nullptr or [BS,512]
    float* __restrict__ C) {        // [BS,512]
  __shared__ float As[16][68];
  __shared__ float Ws[16][68];
  const int tx = threadIdx.x, ty = threadIdx.y;
  const int tid = ty * 16 + tx;
  const int m0 = blockIdx.y * 64, n0 = blockIdx.x * 64;
  const int K = 1024, N = 512;
  const int lr = tid >> 2, lk = (tid & 3) << 2;
  const float* Wp = W + (long)(n0 + lr) * K + lk;
  float acc[4][4] = {};
  for (int k0 = 0; k0 < K; k0 += 16) {
#pragma unroll
    for (int i = 0; i < 4; ++i) {
      int e = tid + i * 256;
      int kk = e >> 6, mm = e & 63;
      int m = m0 + mm;
      int b = m / 196, s = m % 196;
      As[kk][mm] = X[(long)b * 200704 + (long)(k0 + kk) * 196 + s];
    }
    float4 wv = *(const float4*)(Wp + k0);
    Ws[lk + 0][lr] = wv.x; Ws[lk + 1][lr] = wv.y; Ws[lk + 2][lr] = wv.z; Ws[lk + 3][lr] = wv.w;
    __syncthreads();
#pragma unroll
    for (int kk = 0; kk < 16; ++kk) {
      float4 a4 = *(const float4*)&As[kk][ty * 4];
      float4 w4 = *(const float4*)&Ws[kk][tx * 4];
      float a[4] = {a4.x, a4.y, a4.z, a4.w};
      float w[4] = {w4.x, w4.y, w4.z, w4.w};
#pragma unroll
      for (int i = 0; i < 4; ++i)
#pragma unroll
        for (int j = 0; j < 4; ++j) acc[i][j] += a[i] * w[j];
    }
    __syncthreads();
  }
#pragma unroll
  for (int i = 0; i < 4; ++i) {
    int m = m0 + ty * 4 + i;
    int s = m % 196;
#pragma unroll
    for (int j = 0; j < 4; ++j) {
      int n = n0 + tx * 4 + j;
      float pe = (n < 256) ? wemb[(s % 14) * 256 + n] : hemb[(s / 14) * 256 + (n - 256)];
      float v = acc[i][j] + bias[n] + pe;
      if (sub) v -= sub[(long)m * N + n];
      C[(long)m * N + n] = v;
    }
  }
}

// ---- Correlation: C[i,j] += scale * sum_m Za[m,i]*Zb[m,j] (split-K atomic) ----
__global__ __launch_bounds__(256) void k_corr(
    const float* __restrict__ Za, const float* __restrict__ Zb,
    float* __restrict__ C, int mchunk, float scale) {
  __shared__ float As[16][68];
  __shared__ float Bs[16][68];
  const int tx = threadIdx.x, ty = threadIdx.y;
  const int tid = ty * 16 + tx;
  const int i0 = blockIdx.y * 64, j0 = blockIdx.x * 64;
  const int li = (tid & 15) * 4, lm = tid >> 4;
  float acc[4][4] = {};
  const int mstart = blockIdx.z * mchunk;
  for (int m0 = mstart; m0 < mstart + mchunk; m0 += 16) {
    *(float4*)&As[lm][li] = *(const float4*)(Za + (long)(m0 + lm) * 512 + i0 + li);
    *(float4*)&Bs[lm][li] = *(const float4*)(Zb + (long)(m0 + lm) * 512 + j0 + li);
    __syncthreads();
#pragma unroll
    for (int mm = 0; mm < 16; ++mm) {
      float4 a4 = *(const float4*)&As[mm][ty * 4];
      float4 b4 = *(const float4*)&Bs[mm][tx * 4];
      float a[4] = {a4.x, a4.y, a4.z, a4.w};
      float b[4] = {b4.x, b4.y, b4.z, b4.w};
#pragma unroll
      for (int i = 0; i < 4; ++i)
#pragma unroll
        for (int j = 0; j < 4; ++j) acc[i][j] += a[i] * b[j];
    }
    __syncthreads();
  }
#pragma unroll
  for (int i = 0; i < 4; ++i)
#pragma unroll
    for (int j = 0; j < 4; ++j)
      atomicAdd(&C[(long)(i0 + ty * 4 + i) * 512 + j0 + tx * 4 + j], acc[i][j] * scale);
}

// ---- Fused-softmax attention, one block per query row (MHA D=64 only now). ----
__global__ __launch_bounds__(256) void k_attn(
    const float* __restrict__ Q, const float* __restrict__ K, const float* __restrict__ V,
    float* __restrict__ O, int N, int D,
    int64_t qB, int64_t qH, int64_t qR, int64_t kB, int64_t kH, int64_t kR,
    int64_t vB, int64_t vH, int64_t vR, int64_t oB, int64_t oH, int64_t oR,
    float scale, int doClamp) {
  extern __shared__ float sm[];
  float* qs = sm;            // D
  float* p  = sm + D;        // N
  float* po = sm + D + N;    // 256 partials
  __shared__ float red[4];
  const int m = blockIdx.x, h = blockIdx.y, b = blockIdx.z;
  const float* q  = Q + b * qB + h * qH + m * qR;
  const float* Kb = K + b * kB + h * kH;
  const float* Vb = V + b * vB + h * vH;
  float* o = O + b * oB + h * oH + m * oR;
  const int t = threadIdx.x;
  const int lane = t & 63, wid = t >> 6;
  for (int i = t; i < D; i += 256) qs[i] = q[i];
  __syncthreads();
  for (int n = wid; n < N; n += 4) {
    const float* kr = Kb + (long)n * kR;
    float s = 0.f;
#pragma unroll 8
    for (int d = lane; d < D; d += 64) s += qs[d] * kr[d];
#pragma unroll
    for (int off = 32; off > 0; off >>= 1) s += __shfl_down(s, off, 64);
    if (lane == 0) {
      s *= scale;
      if (doClamp) s = fminf(fmaxf(s, -100.f), 100.f);
      p[n] = s;
    }
  }
  __syncthreads();
  float mx = -1e30f;
  for (int n = t; n < N; n += 256) mx = fmaxf(mx, p[n]);
  mx = block_red256(mx, red, true);
  float sum = 0.f;
  for (int n = t; n < N; n += 256) {
    float e = expf(p[n] - mx);
    p[n] = e;
    sum += e;
  }
  sum = block_red256(sum, red, false);
  float inv = 1.0f / sum;
  const int dth = (D < 256) ? D : 256;
  const int nch = 256 / dth;
  const int c = t / dth, d0 = t % dth;
  const int nper = (N + nch - 1) / nch;
  const int ns = c * nper;
  const int ne = (ns + nper < N) ? ns + nper : N;
  for (int d = d0; d < D; d += dth) {
    float acc = 0.f;
    int n = ns;
    for (; n + 4 <= ne; n += 4) {
      float v0 = Vb[(long)(n + 0) * vR + d];
      float v1 = Vb[(long)(n + 1) * vR + d];
      float v2 = Vb[(long)(n + 2) * vR + d];
      float v3 = Vb[(long)(n + 3) * vR + d];
      acc += p[n] * v0 + p[n + 1] * v1 + p[n + 2] * v2 + p[n + 3] * v3;
    }
    for (; n < ne; ++n) acc += p[n] * Vb[(long)n * vR + d];
    if (nch == 1) o[d] = acc * inv;
    else po[c * dth + d] = acc;
  }
  if (nch > 1) {
    __syncthreads();
    if (t < D) {
      float acc = 0.f;
#pragma unroll 4
      for (int cc = 0; cc < nch; ++cc) acc += po[cc * dth + t];
      o[t] = acc * inv;
    }
  }
}

// ---- Residual + LayerNorm (in place into h) ----
__global__ __launch_bounds__(256) void k_addln(
    float* __restrict__ h, const float* __restrict__ o,
    const float* __restrict__ g, const float* __restrict__ be) {
  __shared__ float red[4];
  long row = blockIdx.x;
  float* hr = h + row * 512;
  const float* orow = o + row * 512;
  int t = threadIdx.x;
  float v0 = hr[t] + orow[t];
  float v1 = hr[t + 256] + orow[t + 256];
  float mean = block_red256(v0 + v1, red, false) * (1.0f / 512.0f);
  float d0 = v0 - mean, d1 = v1 - mean;
  float var = block_red256(d0 * d0 + d1 * d1, red, false) * (1.0f / 512.0f);
  float inv = 1.0f / sqrtf(var + 1e-5f);
  hr[t] = d0 * inv * g[t] + be[t];
  hr[t + 256] = d1 * inv * g[t + 256] + be[t + 256];
}

// ---- small utility kernels ----
__global__ void k_zero(float* __restrict__ p, int n) {
  int i = blockIdx.x * 256 + threadIdx.x;
  if (i < n) p[i] = 0.f;
}

__global__ __launch_bounds__(256) void k_colstats(
    const float* __restrict__ f, float* __restrict__ sums, float* __restrict__ sqs) {
  int c = blockIdx.x * 32 + (threadIdx.x & 31);
  int rbase = blockIdx.y * 256;
  int r0 = rbase + (threadIdx.x >> 5);
  float s = 0.f, s2 = 0.f;
  for (int r = r0; r < rbase + 256; r += 8) {
    float v = f[(long)r * 512 + c];
    s += v; s2 += v * v;
  }
  __shared__ float sh[256], sh2[256];
  sh[threadIdx.x] = s; sh2[threadIdx.x] = s2;
  __syncthreads();
  if (threadIdx.x < 32) {
    for (int i = 1; i < 8; ++i) { s += sh[i * 32 + threadIdx.x]; s2 += sh2[i * 32 + threadIdx.x]; }
    atomicAdd(&sums[c], s);
    atomicAdd(&sqs[c], s2);
  }
}

__global__ void k_finstats(const float* __restrict__ sums, const float* __restrict__ sqs,
                           float* __restrict__ mean, float* __restrict__ istd) {
  int c = blockIdx.x * 256 + threadIdx.x;
  float mu = sums[c] / 12544.0f;
  float var = (sqs[c] - 12544.0f * mu * mu) / 12543.0f;
  mean[c] = mu;
  istd[c] = 1.0f / sqrtf(var);
}

__global__ __launch_bounds__(256) void k_znorm(float* __restrict__ f, const float* __restrict__ mean,
                                               const float* __restrict__ istd) {
  long i = (long)blockIdx.x * 256 + threadIdx.x;
  int c = (int)(i & 511);
  f[i] = (f[i] - mean[c]) * istd[c];
}

__global__ __launch_bounds__(256) void k_cdcr(const float* __restrict__ Cm, float* __restrict__ out) {
  __shared__ double s_on[256], s_off[256];
  double on = 0, off = 0;
  for (int i = threadIdx.x; i < 262144; i += 256) {
    float v = Cm[i];
    int r = i >> 9, c = i & 511;
    if (r == c) { double d = (double)v - 1.0; on += d * d; }
    else        { off += (double)v * (double)v; }
  }
  s_on[threadIdx.x] = on; s_off[threadIdx.x] = off;
  __syncthreads();
  for (int st = 128; st > 0; st >>= 1) {
    if (threadIdx.x < st) { s_on[threadIdx.x] += s_on[threadIdx.x + st]; s_off[threadIdx.x] += s_off[threadIdx.x + st]; }
    __syncthreads();
  }
  if (threadIdx.x == 0) out[0] = (float)(s_on[0] + 0.003 * s_off[0]);
}

__global__ __launch_bounds__(64) void k_mask(const float* __restrict__ capo, float* __restrict__ mask) {
  int pidx = blockIdx.x;
  float s = 0.f;
  for (int i = threadIdx.x; i < 512; i += 64) s += capo[(long)pidx * 512 + i];
#pragma unroll
  for (int o = 32; o > 0; o >>= 1) s += __shfl_down(s, o, 64);
  if (threadIdx.x == 0) mask[pidx] = (s != 0.f) ? 1.f : 0.f;
}

__global__ __launch_bounds__(256) void k_meannc(const float* __restrict__ src, const float* __restrict__ mask,
                                                float* __restrict__ vec) {
  int d = blockIdx.x * 256 + threadIdx.x;
  int b = blockIdx.y;
  float acc = 0.f, ms = 0.f;
  for (int nc = 0; nc < 16; ++nc) {
    float mk = mask ? mask[b * 16 + nc] : 1.f;
    acc += src[((long)b * 16 + nc) * 512 + d] * mk;
    ms += mk;
  }
  vec[(long)b * 512 + d] = acc / fmaxf(ms, 1e-6f);
}

__global__ __launch_bounds__(256) void k_mse(const float* __restrict__ full, const float* __restrict__ vec,
                                             double* __restrict__ part) {
  double loc = 0;
  const long n = NOUT;
  for (long i = (long)blockIdx.x * 256 + threadIdx.x; i < n; i += 256L * 1024) {
    int d = (int)(i & 511);
    int b = (int)(i >> 9) / 196;
    float df = full[i] - vec[b * 512 + d];
    loc += (double)df * (double)df;
  }
  __shared__ double sh[256];
  sh[threadIdx.x] = loc;
  __syncthreads();
  for (int st = 128; st > 0; st >>= 1) {
    if (threadIdx.x < st) sh[threadIdx.x] += sh[threadIdx.x + st];
    __syncthreads();
  }
  if (threadIdx.x == 0) part[blockIdx.x] = sh[0];
}

__global__ void k_finloss(const double* __restrict__ part, float* __restrict__ out) {
  __shared__ double sh[256];
  double s = 0;
  for (int i = threadIdx.x; i < 4096; i += 256) s += part[i];
  sh[threadIdx.x] = s;
  __syncthreads();
  for (int st = 128; st > 0; st >>= 1) {
    if (threadIdx.x < st) sh[threadIdx.x] += sh[threadIdx.x + st];
    __syncthreads();
  }
  if (threadIdx.x == 0) out[0] = (float)(sh[0] / (64.0 * 196.0 * 512.0));
}

__global__ __launch_bounds__(256) void k_concat2(float* __restrict__ dst, const float* __restrict__ a,
                                                 const float* __restrict__ b) {
  int i = blockIdx.x * 256 + threadIdx.x;   // 64*1024
  int col = i & 1023, row = i >> 10;
  dst[i] = (col < 512) ? a[row * 512 + col] : b[row * 512 + col - 512];
}

// comb chunk: rows [r0, r0+3136) of [BS,2048] into dst
__global__ __launch_bounds__(256) void k_comb_chunk(
    float* __restrict__ dst, const float* __restrict__ d1, const float* __restrict__ d2,
    const float* __restrict__ txt, const float* __restrict__ al, long r0) {
  long i = (long)blockIdx.x * 256 + threadIdx.x;  // 3136*2048
  int col = (int)(i & 2047);
  long m = r0 + (i >> 11);
  int b = (int)(m / 196);
  float v;
  if (col < 512)       v = d1[m * 512 + col];
  else if (col < 1024) v = d2[m * 512 + col - 512];
  else if (col < 1536) v = txt[(long)b * 512 + col - 1024];
  else                 v = al[(long)b * 512 + col - 1536];
  dst[i] = v;
}

// ---------------- host ----------------
extern "C" void kernel_launch(void* const* d_in, const int* in_sizes, int n_in,
                              void* d_out, int out_size, void* d_ws, size_t ws_size,
                              hipStream_t stream) {
  (void)in_sizes; (void)n_in; (void)out_size; (void)ws_size;
  const float* in1    = (const float*)d_in[0];
  const float* in2    = (const float*)d_in[1];
  const float* cap1   = (const float*)d_in[2];
  const float* cap2   = (const float*)d_in[3];
  const float* imgw   = (const float*)d_in[4];
  const float* imgb   = (const float*)d_in[5];
  const float* wemb   = (const float*)d_in[6];
  const float* hemb   = (const float*)d_in[7];
  const float* mlpw1  = (const float*)d_in[8];
  const float* mlpb1  = (const float*)d_in[9];
  const float* mlpw2  = (const float*)d_in[10];
  const float* mlpb2  = (const float*)d_in[11];
  const float* fcw    = (const float*)d_in[12];
  const float* fcb    = (const float*)d_in[13];
  const float* efcw   = (const float*)d_in[14];
  const float* efcb   = (const float*)d_in[15];
  const float* efc2w  = (const float*)d_in[16];
  const float* efc2b  = (const float*)d_in[17];
  const float* trinw  = (const float*)d_in[18];
  const float* trinb  = (const float*)d_in[19];
  const float* troutw = (const float*)d_in[20];
  const float* troutb = (const float*)d_in[21];
  const float* trlng  = (const float*)d_in[22];
  const float* trlnb  = (const float*)d_in[23];
  const float* itqw = (const float*)d_in[24]; const float* itqb = (const float*)d_in[25];
  const float* itkw = (const float*)d_in[26]; const float* itkb = (const float*)d_in[27];
  const float* itvw = (const float*)d_in[28]; const float* itvb = (const float*)d_in[29];
  const float* caqw = (const float*)d_in[30]; const float* caqb = (const float*)d_in[31];
  const float* cakw = (const float*)d_in[32]; const float* cakb = (const float*)d_in[33];
  const float* cavw = (const float*)d_in[34]; const float* cavb = (const float*)d_in[35];
  const float* saqw = (const float*)d_in[36]; const float* saqb = (const float*)d_in[37];
  const float* sakw = (const float*)d_in[38]; const float* sakb = (const float*)d_in[39];
  const float* savw = (const float*)d_in[40]; const float* savb = (const float*)d_in[41];

  float* out = (float*)d_out;

  // ---- workspace carve (~171 MB total) ----
  const size_t SZ = (size_t)BS * 512;        // 6,422,528 floats (24.5 MB)
  float* w = (float*)d_ws;
  auto alloc = [&](size_t n) { float* p = w; w += n; return p; };
  float* h1 = alloc(SZ);
  float* h2 = alloc(SZ);
  float* tA = alloc(SZ);
  float* tB = alloc(SZ);
  float* tC = alloc(SZ);
  float* tD = alloc(SZ);
  float* sbuf = alloc((size_t)64 * 196 * 208);   // 2.61M floats: attention scores
  float* cap1o = alloc(64 * 16 * 512);
  float* cap2o = alloc(64 * 16 * 512);
  float* qc1   = alloc(64 * 16 * 512);
  float* qc2   = alloc(64 * 16 * 512);
  float* attb  = alloc(64 * 16 * 512);
  float* cmat  = alloc(512 * 512);
  float* colsum1 = alloc(512); float* colsq1 = alloc(512);
  float* colsum2 = alloc(512); float* colsq2 = alloc(512);
  float* mean1 = alloc(512); float* istd1 = alloc(512);
  float* mean2 = alloc(512); float* istd2 = alloc(512);
  float* mask1 = alloc(1024); float* mask2 = alloc(1024);
  float* vdbef = alloc(64 * 512); float* vdaft = alloc(64 * 512);
  float* vsbef = alloc(64 * 512); float* vsaft = alloc(64 * 512);
  float* cm1 = alloc(64 * 512); float* cm2 = alloc(64 * 512);
  float* vdyn = alloc(64 * 512); float* vsta = alloc(64 * 512);
  float* valign = alloc(64 * 512); float* vtxt = alloc(64 * 512);
  float* ccat = alloc(64 * 1024);
  double* msepart = (double*)alloc(4096 * 2);  // 4096 doubles

  auto gemm = [&](const float* Aa, const float* Ww, const float* bb, float* Cc,
                  int M, int N, int K, int relu) {
    k_gemm_nt<<<dim3(N / 64, M / 64), dim3(16, 16), 0, stream>>>(Aa, Ww, bb, Cc, M, N, K, relu);
  };
  auto attn = [&](const float* Qp, const float* Kp, const float* Vp, float* Op,
                  int M, int H, int N, int D,
                  int64_t qB, int64_t qH, int64_t qR,
                  int64_t kB, int64_t kH, int64_t kR,
                  int64_t vB, int64_t vH, int64_t vR,
                  int64_t oB, int64_t oH, int64_t oR,
                  float scale, int clampf) {
    size_t smem = (size_t)(D + N + 256) * sizeof(float);
    k_attn<<<dim3(M, H, BB), 256, smem, stream>>>(Qp, Kp, Vp, Op, N, D,
        qB, qH, qR, kB, kH, kR, vB, vH, vR, oB, oH, oR, scale, clampf);
  };
  auto embed = [&](const float* X, const float* sub, float* Cc) {
    k_gemm_embed<<<dim3(8, BS / 64), dim3(16, 16), 0, stream>>>(X, imgw, imgb, wemb, hemb, sub, Cc);
  };
  // GEMM-ized attention for D=512 single-head cases (ECA: M=196, ITDA: M=16)
  auto attn512 = [&](const float* Qp, const float* Kp, const float* Vp, float* Op,
                     int M, int64_t qZ, int64_t oZ, float scale) {
    int mt = (M + 63) / 64;
    int64_t sS = (int64_t)M * 208;
    k_bgemm_nt<<<dim3((196 + 63) / 64, mt, 64), dim3(16, 16), 0, stream>>>(
        Qp, Kp, sbuf, M, 196, 512, 512, 512, 208, 1,
        qZ, 0, (int64_t)196 * 512, 0, sS, 0, scale, 1);
    k_softmax_rows<<<(64 * M + 3) / 4, 256, 0, stream>>>(sbuf, 64 * M);
    k_bgemm_nn<<<dim3(8, mt, 64), dim3(16, 16), 0, stream>>>(
        sbuf, Vp, Op, M, 512, 208, 196, 208, 512, 512, 1,
        sS, 0, (int64_t)196 * 512, 0, oZ, 0);
  };

  const float scalE = 1.0f / sqrtf(512.0f);
  const int64_t RB = (int64_t)SS * 512;  // 100352
  const int64_t QB = 16 * 512;           // 8192

  // ---- Phase 1: embed (h starts as x) + caption projections ----
  embed(in1, nullptr, h1);
  embed(in2, nullptr, h2);
  gemm(cap1, fcw, fcb, cap1o, 1024, 512, 768, 0);
  gemm(cap2, fcw, fcb, cap2o, 1024, 512, 768, 0);
  k_meannc<<<dim3(2, 64), 256, 0, stream>>>(cap1o, nullptr, cm1);
  k_meannc<<<dim3(2, 64), 256, 0, stream>>>(cap2o, nullptr, cm2);

  // ---- Phase 2: CDCR loss (f1->tA, f2->tB, hidden chunk in tC) ----
  for (int c = 0; c < 4; ++c) {
    const size_t off = (size_t)c * 3136 * 512;
    gemm(h1 + off, mlpw1, mlpb1, tC, 3136, 2048, 512, 1);
    gemm(tC, mlpw2, mlpb2, tA + off, 3136, 512, 2048, 0);
  }
  for (int c = 0; c < 4; ++c) {
    const size_t off = (size_t)c * 3136 * 512;
    gemm(h2 + off, mlpw1, mlpb1, tC, 3136, 2048, 512, 1);
    gemm(tC, mlpw2, mlpb2, tB + off, 3136, 512, 2048, 0);
  }
  k_zero<<<8, 256, 0, stream>>>(colsum1, 2048);  // colsum1..colsq2 contiguous
  k_colstats<<<dim3(16, 49), 256, 0, stream>>>(tA, colsum1, colsq1);
  k_colstats<<<dim3(16, 49), 256, 0, stream>>>(tB, colsum2, colsq2);
  k_finstats<<<2, 256, 0, stream>>>(colsum1, colsq1, mean1, istd1);
  k_finstats<<<2, 256, 0, stream>>>(colsum2, colsq2, mean2, istd2);
  k_znorm<<<25088, 256, 0, stream>>>(tA, mean1, istd1);
  k_znorm<<<25088, 256, 0, stream>>>(tB, mean2, istd2);
  k_zero<<<1024, 256, 0, stream>>>(cmat, 262144);
  k_corr<<<dim3(8, 8, 8), dim3(16, 16), 0, stream>>>(tA, tB, cmat, BS / 8, 1.0f / (float)BS);
  k_cdcr<<<1, 256, 0, stream>>>(cmat, out + NOUT);

  // ---- Phase 3: cross-transformer (2 layers, simultaneous update) ----
  for (int l = 0; l < 2; ++l) {
    const float* Wq = trinw + (size_t)l * 1536 * 512;
    const float* Wk = Wq + 512 * 512;
    const float* Wv = Wq + 2 * 512 * 512;
    const float* bq = trinb + l * 1536;
    const float* bk = bq + 512;
    const float* bv = bq + 1024;
    const float* Wo = troutw + (size_t)l * 512 * 512;
    const float* bo = troutb + l * 512;
    const float* g  = trlng + l * 512;
    const float* be = trlnb + l * 512;
    // dir1: q=h1, kv=h2
    gemm(h1, Wq, bq, tA, BS, 512, 512, 0);
    gemm(h2, Wk, bk, tB, BS, 512, 512, 0);
    gemm(h2, Wv, bv, tC, BS, 512, 512, 0);
    attn(tA, tB, tC, tA, SS, 8, SS, 64, RB, 64, 512, RB, 64, 512, RB, 64, 512, RB, 64, 512, 0.125f, 0);
    gemm(tA, Wo, bo, tD, BS, 512, 512, 0);       // o1 -> tD
    // dir2 projections from ORIGINAL h1,h2
    gemm(h2, Wq, bq, tA, BS, 512, 512, 0);
    gemm(h1, Wk, bk, tB, BS, 512, 512, 0);
    gemm(h1, Wv, bv, tC, BS, 512, 512, 0);
    k_addln<<<BS, 256, 0, stream>>>(h1, tD, g, be);  // h1 consumed above; update now
    attn(tA, tB, tC, tA, SS, 8, SS, 64, RB, 64, 512, RB, 64, 512, RB, 64, 512, RB, 64, 512, 0.125f, 0);
    gemm(tA, Wo, bo, tD, BS, 512, 512, 0);       // o2 -> tD
    k_addln<<<BS, 256, 0, stream>>>(h2, tD, g, be);
  }

  // ---- Phase 4: diffs via embed recompute (deterministic, bitwise-equal x) ----
  embed(in1, h1, tC);   // diff1 = x1 - h1
  embed(in2, h2, tD);   // diff2 = x2 - h2
  // h1, h2 now free

  // ---- Phase 5: ITDA (queries constant over S -> per-(b,nc) attention + masked mean) ----
  gemm(cap1o, itqw, itqb, qc1, 1024, 512, 512, 0);
  gemm(cap2o, itqw, itqb, qc2, 1024, 512, 512, 0);
  k_mask<<<1024, 64, 0, stream>>>(cap1o, mask1);
  k_mask<<<1024, 64, 0, stream>>>(cap2o, mask2);
  // K1,V1 from diff1
  gemm(tC, itkw, itkb, tA, BS, 512, 512, 0);
  gemm(tC, itvw, itvb, tB, BS, 512, 512, 0);
  attn512(qc2, tA, tB, attb, 16, QB, QB, scalE);
  k_meannc<<<dim3(2, 64), 256, 0, stream>>>(attb, mask2, vdbef);   // d_bef
  attn512(qc1, tA, tB, attb, 16, QB, QB, scalE);
  k_meannc<<<dim3(2, 64), 256, 0, stream>>>(attb, mask1, vsbef);   // s_bef
  // K2,V2 from diff2
  gemm(tD, itkw, itkb, tA, BS, 512, 512, 0);
  gemm(tD, itvw, itvb, tB, BS, 512, 512, 0);
  attn512(qc1, tA, tB, attb, 16, QB, QB, scalE);
  k_meannc<<<dim3(2, 64), 256, 0, stream>>>(attb, mask1, vdaft);   // d_aft
  attn512(qc2, tA, tB, attb, 16, QB, QB, scalE);
  k_meannc<<<dim3(2, 64), 256, 0, stream>>>(attb, mask2, vsaft);   // s_aft

  // ---- Phase 6: ECA x4 with immediate MSE vs ITDA vector ----
  auto eca_mse = [&](const float* xq, const float* xkv,
                     const float* qw2, const float* qb2, const float* kw2, const float* kb2,
                     const float* vw2, const float* vb2, const float* vec, double* part) {
    gemm(xq,  qw2, qb2, tA, BS, 512, 512, 0);
    gemm(xkv, kw2, kb2, tB, BS, 512, 512, 0);
    gemm(xkv, vw2, vb2, h1, BS, 512, 512, 0);
    attn512(tA, tB, h1, tA, 196, RB, RB, scalE);
    k_mse<<<1024, 256, 0, stream>>>(tA, vec, part);
  };
  eca_mse(tC, tD, caqw, caqb, cakw, cakb, cavw, cavb, vdbef, msepart);          // c12 vs d_bef
  eca_mse(tD, tC, caqw, caqb, cakw, cakb, cavw, cavb, vdaft, msepart + 1024);   // c21 vs d_aft
  eca_mse(tC, tC, saqw, saqb, sakw, sakb, savw, savb, vsbef, msepart + 2048);   // s11 vs s_bef
  eca_mse(tD, tD, saqw, saqb, sakw, sakb, savw, savb, vsaft, msepart + 3072);   // s22 vs s_aft
  k_finloss<<<1, 256, 0, stream>>>(msepart, out + NOUT + 1);

  // ---- Phase 7: efc chain (per-batch vectors) ----
  k_concat2<<<256, 256, 0, stream>>>(ccat, vdbef, vdaft);
  gemm(ccat, efcw, efcb, vdyn, 64, 512, 1024, 1);
  k_concat2<<<256, 256, 0, stream>>>(ccat, vsbef, vsaft);
  gemm(ccat, efcw, efcb, vsta, 64, 512, 1024, 1);
  k_concat2<<<256, 256, 0, stream>>>(ccat, vdyn, vsta);
  gemm(ccat, efcw, efcb, valign, 64, 512, 1024, 1);
  k_concat2<<<256, 256, 0, stream>>>(ccat, cm1, cm2);
  gemm(ccat, efcw, efcb, vtxt, 64, 512, 1024, 1);

  // ---- Phase 8: final projection, chunked comb (3136 rows/chunk) ----
  for (int c = 0; c < 4; ++c) {
    long r0 = (long)c * 3136;
    k_comb_chunk<<<25088, 256, 0, stream>>>(tA, tC, tD, vtxt, valign, r0);
    gemm(tA, efc2w, efc2b, out + r0 * 512, 3136, 512, 2048, 1);
  }
}

// Round 5
// 9350.812 us; speedup vs baseline: 1.8060x; 1.6632x over previous
//
#include <hip/hip_runtime.h>
#include <stdint.h>
#include <math.h>

// Problem constants
#define BB   64
#define SS   196
#define BS   12544            // BB*SS
#define NOUT 6422528L         // BS*512

// ---------------- device helpers ----------------
__device__ __forceinline__ float block_red256(float v, float* red, bool ismax) {
#pragma unroll
  for (int o = 32; o > 0; o >>= 1) {
    float t = __shfl_down(v, o, 64);
    v = ismax ? fmaxf(v, t) : v + t;
  }
  int lane = threadIdx.x & 63, wid = threadIdx.x >> 6;
  if (lane == 0) red[wid] = v;
  __syncthreads();
  float r = ismax ? fmaxf(fmaxf(red[0], red[1]), fmaxf(red[2], red[3]))
                  : (red[0] + red[1]) + (red[2] + red[3]);
  __syncthreads();
  return r;
}

// ---------------- GEMM: C[M,N] = A[M,K] @ W[N,K]^T + bias (opt relu) ----------------
__global__ __launch_bounds__(256) void k_gemm_nt(
    const float* __restrict__ A, const float* __restrict__ W,
    const float* __restrict__ bias, float* __restrict__ C,
    int M, int N, int K, int relu) {
  __shared__ float As[16][68];
  __shared__ float Ws[16][68];
  const int tx = threadIdx.x, ty = threadIdx.y;
  const int tid = ty * 16 + tx;
  const int m0 = blockIdx.y * 64, n0 = blockIdx.x * 64;
  const int lr = tid >> 2, lk = (tid & 3) << 2;
  const float* Ap = A + (long)(m0 + lr) * K + lk;
  const float* Wp = W + (long)(n0 + lr) * K + lk;
  float acc[4][4] = {};
  for (int k0 = 0; k0 < K; k0 += 16) {
    float4 av = *(const float4*)(Ap + k0);
    float4 wv = *(const float4*)(Wp + k0);
    As[lk + 0][lr] = av.x; As[lk + 1][lr] = av.y; As[lk + 2][lr] = av.z; As[lk + 3][lr] = av.w;
    Ws[lk + 0][lr] = wv.x; Ws[lk + 1][lr] = wv.y; Ws[lk + 2][lr] = wv.z; Ws[lk + 3][lr] = wv.w;
    __syncthreads();
#pragma unroll
    for (int kk = 0; kk < 16; ++kk) {
      float4 a4 = *(const float4*)&As[kk][ty * 4];
      float4 w4 = *(const float4*)&Ws[kk][tx * 4];
      float a[4] = {a4.x, a4.y, a4.z, a4.w};
      float w[4] = {w4.x, w4.y, w4.z, w4.w};
#pragma unroll
      for (int i = 0; i < 4; ++i)
#pragma unroll
        for (int j = 0; j < 4; ++j) acc[i][j] += a[i] * w[j];
    }
    __syncthreads();
  }
#pragma unroll
  for (int i = 0; i < 4; ++i) {
    int m = m0 + ty * 4 + i;
#pragma unroll
    for (int j = 0; j < 4; ++j) {
      int n = n0 + tx * 4 + j;
      float v = acc[i][j] + bias[n];
      if (relu) v = fmaxf(v, 0.f);
      C[(long)m * N + n] = v;
    }
  }
}

// ---- Batched NT GEMM: C[z][m,n] = scale * sum_k A[z][m,k]*B[z][n,k], opt clamp ----
// z = z1*nz2 + z2 for dual batch strides. M,N bounds-checked (row clamp for loads).
__global__ __launch_bounds__(256) void k_bgemm_nt(
    const float* __restrict__ A, const float* __restrict__ B, float* __restrict__ C,
    int M, int N, int K, int lda, int ldb, int ldc, int nz2,
    int64_t sA1, int64_t sA2, int64_t sB1, int64_t sB2, int64_t sC1, int64_t sC2,
    float scale, int clampf) {
  __shared__ float As[16][68];
  __shared__ float Bs[16][68];
  const int tx = threadIdx.x, ty = threadIdx.y;
  const int tid = ty * 16 + tx;
  const int m0 = blockIdx.y * 64, n0 = blockIdx.x * 64;
  const int z = blockIdx.z;
  const int z1 = z / nz2, z2 = z % nz2;
  const float* Ab = A + z1 * sA1 + z2 * sA2;
  const float* Bb = B + z1 * sB1 + z2 * sB2;
  float* Cb = C + z1 * sC1 + z2 * sC2;
  const int lr = tid >> 2, lk = (tid & 3) << 2;
  const int ar = (m0 + lr < M) ? m0 + lr : M - 1;
  const int br = (n0 + lr < N) ? n0 + lr : N - 1;
  const float* Ap = Ab + (long)ar * lda + lk;
  const float* Bp = Bb + (long)br * ldb + lk;
  float acc[4][4] = {};
  for (int k0 = 0; k0 < K; k0 += 16) {
    float4 av = *(const float4*)(Ap + k0);
    float4 bv = *(const float4*)(Bp + k0);
    As[lk + 0][lr] = av.x; As[lk + 1][lr] = av.y; As[lk + 2][lr] = av.z; As[lk + 3][lr] = av.w;
    Bs[lk + 0][lr] = bv.x; Bs[lk + 1][lr] = bv.y; Bs[lk + 2][lr] = bv.z; Bs[lk + 3][lr] = bv.w;
    __syncthreads();
#pragma unroll
    for (int kk = 0; kk < 16; ++kk) {
      float4 a4 = *(const float4*)&As[kk][ty * 4];
      float4 b4 = *(const float4*)&Bs[kk][tx * 4];
      float a[4] = {a4.x, a4.y, a4.z, a4.w};
      float b[4] = {b4.x, b4.y, b4.z, b4.w};
#pragma unroll
      for (int i = 0; i < 4; ++i)
#pragma unroll
        for (int j = 0; j < 4; ++j) acc[i][j] += a[i] * b[j];
    }
    __syncthreads();
  }
#pragma unroll
  for (int i = 0; i < 4; ++i) {
    int m = m0 + ty * 4 + i;
    if (m >= M) continue;
#pragma unroll
    for (int j = 0; j < 4; ++j) {
      int n = n0 + tx * 4 + j;
      if (n >= N) continue;
      float v = acc[i][j] * scale;
      if (clampf) v = fminf(fmaxf(v, -100.f), 100.f);
      Cb[(long)m * ldc + n] = v;
    }
  }
}

// ---- Batched NN GEMM: C[z][m,n] = sum_k A[z][m,k]*B[z][k,n]. K mult of 16;
// B k-rows clamped to KBvalid-1 (A pad cols are zero so product is exact). ----
__global__ __launch_bounds__(256) void k_bgemm_nn(
    const float* __restrict__ A, const float* __restrict__ B, float* __restrict__ C,
    int M, int N, int K, int KBvalid, int lda, int ldb, int ldc, int nz2,
    int64_t sA1, int64_t sA2, int64_t sB1, int64_t sB2, int64_t sC1, int64_t sC2) {
  __shared__ float As[16][68];
  __shared__ float Bs[16][68];
  const int tx = threadIdx.x, ty = threadIdx.y;
  const int tid = ty * 16 + tx;
  const int m0 = blockIdx.y * 64, n0 = blockIdx.x * 64;
  const int z = blockIdx.z;
  const int z1 = z / nz2, z2 = z % nz2;
  const float* Ab = A + z1 * sA1 + z2 * sA2;
  const float* Bb = B + z1 * sB1 + z2 * sB2;
  float* Cb = C + z1 * sC1 + z2 * sC2;
  const int lr = tid >> 2, lk = (tid & 3) << 2;
  const int ar = (m0 + lr < M) ? m0 + lr : M - 1;
  const float* Ap = Ab + (long)ar * lda + lk;
  const int bk = tid >> 6, bn = tid & 63;   // B staging: 4 k-rows x 64 n-cols
  float acc[4][4] = {};
  for (int k0 = 0; k0 < K; k0 += 16) {
    float4 av = *(const float4*)(Ap + k0);
    As[lk + 0][lr] = av.x; As[lk + 1][lr] = av.y; As[lk + 2][lr] = av.z; As[lk + 3][lr] = av.w;
#pragma unroll
    for (int kko = 0; kko < 16; kko += 4) {
      int k = k0 + bk + kko;
      int kc = (k < KBvalid) ? k : KBvalid - 1;
      Bs[bk + kko][bn] = Bb[(long)kc * ldb + n0 + bn];
    }
    __syncthreads();
#pragma unroll
    for (int kk = 0; kk < 16; ++kk) {
      float4 a4 = *(const float4*)&As[kk][ty * 4];
      float4 b4 = *(const float4*)&Bs[kk][tx * 4];
      float a[4] = {a4.x, a4.y, a4.z, a4.w};
      float b[4] = {b4.x, b4.y, b4.z, b4.w};
#pragma unroll
      for (int i = 0; i < 4; ++i)
#pragma unroll
        for (int j = 0; j < 4; ++j) acc[i][j] += a[i] * b[j];
    }
    __syncthreads();
  }
#pragma unroll
  for (int i = 0; i < 4; ++i) {
    int m = m0 + ty * 4 + i;
    if (m >= M) continue;
#pragma unroll
    for (int j = 0; j < 4; ++j) {
      int n = n0 + tx * 4 + j;
      if (n >= N) continue;
      Cb[(long)m * ldc + n] = acc[i][j];
    }
  }
}

// ---- Row softmax over rows of width 196, ld=208; zeroes pad cols. 1 wave/row. ----
__global__ __launch_bounds__(256) void k_softmax_rows(float* __restrict__ S, int nrows) {
  int row = blockIdx.x * 4 + (threadIdx.x >> 6);
  int lane = threadIdx.x & 63;
  if (row >= nrows) return;
  float* p = S + (long)row * 208;
  float v0 = p[lane];
  float v1 = p[lane + 64];
  float v2 = p[lane + 128];
  float v3 = (lane + 192 < 196) ? p[lane + 192] : -1e30f;
  float mx = fmaxf(fmaxf(v0, v1), fmaxf(v2, v3));
#pragma unroll
  for (int o = 32; o > 0; o >>= 1) mx = fmaxf(mx, __shfl_down(mx, o, 64));
  mx = __shfl(mx, 0, 64);
  float e0 = expf(v0 - mx), e1 = expf(v1 - mx), e2 = expf(v2 - mx);
  float e3 = (lane + 192 < 196) ? expf(v3 - mx) : 0.f;
  float s = e0 + e1 + e2 + e3;
#pragma unroll
  for (int o = 32; o > 0; o >>= 1) s += __shfl_down(s, o, 64);
  s = __shfl(s, 0, 64);
  float inv = 1.0f / s;
  p[lane] = e0 * inv;
  p[lane + 64] = e1 * inv;
  p[lane + 128] = e2 * inv;
  if (lane + 192 < 208) p[lane + 192] = (lane + 192 < 196) ? e3 * inv : 0.f;
}

// ---- Embed GEMM: C[b,s,a] = sum_c X[b,c,s]*W[a,c] + bias[a] + pe[s,a] - sub[b,s,a] ----
__global__ __launch_bounds__(256) void k_gemm_embed(
    const float* __restrict__ X,   // [B,1024,196]
    const float* __restrict__ W,   // [512,1024]
    const float* __restrict__ bias,
    const float* __restrict__ wemb, const float* __restrict__ hemb,
    const float* __restrict__ sub,  // nullptr or [BS,512]
    float* __restrict__ C) {        // [BS,512]
  __shared__ float As[16][68];
  __shared__ float Ws[16][68];
  const int tx = threadIdx.x, ty = threadIdx.y;
  const int tid = ty * 16 + tx;
  const int m0 = blockIdx.y * 64, n0 = blockIdx.x * 64;
  const int K = 1024, N = 512;
  const int lr = tid >> 2, lk = (tid & 3) << 2;
  const float* Wp = W + (long)(n0 + lr) * K + lk;
  float acc[4][4] = {};
  for (int k0 = 0; k0 < K; k0 += 16) {
#pragma unroll
    for (int i = 0; i < 4; ++i) {
      int e = tid + i * 256;
      int kk = e >> 6, mm = e & 63;
      int m = m0 + mm;
      int b = m / 196, s = m % 196;
      As[kk][mm] = X[(long)b * 200704 + (long)(k0 + kk) * 196 + s];
    }
    float4 wv = *(const float4*)(Wp + k0);
    Ws[lk + 0][lr] = wv.x; Ws[lk + 1][lr] = wv.y; Ws[lk + 2][lr] = wv.z; Ws[lk + 3][lr] = wv.w;
    __syncthreads();
#pragma unroll
    for (int kk = 0; kk < 16; ++kk) {
      float4 a4 = *(const float4*)&As[kk][ty * 4];
      float4 w4 = *(const float4*)&Ws[kk][tx * 4];
      float a[4] = {a4.x, a4.y, a4.z, a4.w};
      float w[4] = {w4.x, w4.y, w4.z, w4.w};
#pragma unroll
      for (int i = 0; i < 4; ++i)
#pragma unroll
        for (int j = 0; j < 4; ++j) acc[i][j] += a[i] * w[j];
    }
    __syncthreads();
  }
#pragma unroll
  for (int i = 0; i < 4; ++i) {
    int m = m0 + ty * 4 + i;
    int s = m % 196;
#pragma unroll
    for (int j = 0; j < 4; ++j) {
      int n = n0 + tx * 4 + j;
      float pe = (n < 256) ? wemb[(s % 14) * 256 + n] : hemb[(s / 14) * 256 + (n - 256)];
      float v = acc[i][j] + bias[n] + pe;
      if (sub) v -= sub[(long)m * N + n];
      C[(long)m * N + n] = v;
    }
  }
}

// ---- Correlation: C[i,j] += scale * sum_m Za[m,i]*Zb[m,j] (split-K atomic) ----
__global__ __launch_bounds__(256) void k_corr(
    const float* __restrict__ Za, const float* __restrict__ Zb,
    float* __restrict__ C, int mchunk, float scale) {
  __shared__ float As[16][68];
  __shared__ float Bs[16][68];
  const int tx = threadIdx.x, ty = threadIdx.y;
  const int tid = ty * 16 + tx;
  const int i0 = blockIdx.y * 64, j0 = blockIdx.x * 64;
  const int li = (tid & 15) * 4, lm = tid >> 4;
  float acc[4][4] = {};
  const int mstart = blockIdx.z * mchunk;
  for (int m0 = mstart; m0 < mstart + mchunk; m0 += 16) {
    *(float4*)&As[lm][li] = *(const float4*)(Za + (long)(m0 + lm) * 512 + i0 + li);
    *(float4*)&Bs[lm][li] = *(const float4*)(Zb + (long)(m0 + lm) * 512 + j0 + li);
    __syncthreads();
#pragma unroll
    for (int mm = 0; mm < 16; ++mm) {
      float4 a4 = *(const float4*)&As[mm][ty * 4];
      float4 b4 = *(const float4*)&Bs[mm][tx * 4];
      float a[4] = {a4.x, a4.y, a4.z, a4.w};
      float b[4] = {b4.x, b4.y, b4.z, b4.w};
#pragma unroll
      for (int i = 0; i < 4; ++i)
#pragma unroll
        for (int j = 0; j < 4; ++j) acc[i][j] += a[i] * b[j];
    }
    __syncthreads();
  }
#pragma unroll
  for (int i = 0; i < 4; ++i)
#pragma unroll
    for (int j = 0; j < 4; ++j)
      atomicAdd(&C[(long)(i0 + ty * 4 + i) * 512 + j0 + tx * 4 + j], acc[i][j] * scale);
}

// ---- Residual + LayerNorm (in place into h) ----
__global__ __launch_bounds__(256) void k_addln(
    float* __restrict__ h, const float* __restrict__ o,
    const float* __restrict__ g, const float* __restrict__ be) {
  __shared__ float red[4];
  long row = blockIdx.x;
  float* hr = h + row * 512;
  const float* orow = o + row * 512;
  int t = threadIdx.x;
  float v0 = hr[t] + orow[t];
  float v1 = hr[t + 256] + orow[t + 256];
  float mean = block_red256(v0 + v1, red, false) * (1.0f / 512.0f);
  float d0 = v0 - mean, d1 = v1 - mean;
  float var = block_red256(d0 * d0 + d1 * d1, red, false) * (1.0f / 512.0f);
  float inv = 1.0f / sqrtf(var + 1e-5f);
  hr[t] = d0 * inv * g[t] + be[t];
  hr[t + 256] = d1 * inv * g[t + 256] + be[t + 256];
}

// ---- small utility kernels ----
__global__ void k_zero(float* __restrict__ p, int n) {
  int i = blockIdx.x * 256 + threadIdx.x;
  if (i < n) p[i] = 0.f;
}

__global__ __launch_bounds__(256) void k_colstats(
    const float* __restrict__ f, float* __restrict__ sums, float* __restrict__ sqs) {
  int c = blockIdx.x * 32 + (threadIdx.x & 31);
  int rbase = blockIdx.y * 256;
  int r0 = rbase + (threadIdx.x >> 5);
  float s = 0.f, s2 = 0.f;
  for (int r = r0; r < rbase + 256; r += 8) {
    float v = f[(long)r * 512 + c];
    s += v; s2 += v * v;
  }
  __shared__ float sh[256], sh2[256];
  sh[threadIdx.x] = s; sh2[threadIdx.x] = s2;
  __syncthreads();
  if (threadIdx.x < 32) {
    for (int i = 1; i < 8; ++i) { s += sh[i * 32 + threadIdx.x]; s2 += sh2[i * 32 + threadIdx.x]; }
    atomicAdd(&sums[c], s);
    atomicAdd(&sqs[c], s2);
  }
}

__global__ void k_finstats(const float* __restrict__ sums, const float* __restrict__ sqs,
                           float* __restrict__ mean, float* __restrict__ istd) {
  int c = blockIdx.x * 256 + threadIdx.x;
  float mu = sums[c] / 12544.0f;
  float var = (sqs[c] - 12544.0f * mu * mu) / 12543.0f;
  mean[c] = mu;
  istd[c] = 1.0f / sqrtf(var);
}

__global__ __launch_bounds__(256) void k_znorm(float* __restrict__ f, const float* __restrict__ mean,
                                               const float* __restrict__ istd) {
  long i = (long)blockIdx.x * 256 + threadIdx.x;
  int c = (int)(i & 511);
  f[i] = (f[i] - mean[c]) * istd[c];
}

__global__ __launch_bounds__(256) void k_cdcr(const float* __restrict__ Cm, float* __restrict__ out) {
  __shared__ double s_on[256], s_off[256];
  double on = 0, off = 0;
  for (int i = threadIdx.x; i < 262144; i += 256) {
    float v = Cm[i];
    int r = i >> 9, c = i & 511;
    if (r == c) { double d = (double)v - 1.0; on += d * d; }
    else        { off += (double)v * (double)v; }
  }
  s_on[threadIdx.x] = on; s_off[threadIdx.x] = off;
  __syncthreads();
  for (int st = 128; st > 0; st >>= 1) {
    if (threadIdx.x < st) { s_on[threadIdx.x] += s_on[threadIdx.x + st]; s_off[threadIdx.x] += s_off[threadIdx.x + st]; }
    __syncthreads();
  }
  if (threadIdx.x == 0) out[0] = (float)(s_on[0] + 0.003 * s_off[0]);
}

__global__ __launch_bounds__(64) void k_mask(const float* __restrict__ capo, float* __restrict__ mask) {
  int pidx = blockIdx.x;
  float s = 0.f;
  for (int i = threadIdx.x; i < 512; i += 64) s += capo[(long)pidx * 512 + i];
#pragma unroll
  for (int o = 32; o > 0; o >>= 1) s += __shfl_down(s, o, 64);
  if (threadIdx.x == 0) mask[pidx] = (s != 0.f) ? 1.f : 0.f;
}

__global__ __launch_bounds__(256) void k_meannc(const float* __restrict__ src, const float* __restrict__ mask,
                                                float* __restrict__ vec) {
  int d = blockIdx.x * 256 + threadIdx.x;
  int b = blockIdx.y;
  float acc = 0.f, ms = 0.f;
  for (int nc = 0; nc < 16; ++nc) {
    float mk = mask ? mask[b * 16 + nc] : 1.f;
    acc += src[((long)b * 16 + nc) * 512 + d] * mk;
    ms += mk;
  }
  vec[(long)b * 512 + d] = acc / fmaxf(ms, 1e-6f);
}

__global__ __launch_bounds__(256) void k_mse(const float* __restrict__ full, const float* __restrict__ vec,
                                             double* __restrict__ part) {
  double loc = 0;
  const long n = NOUT;
  for (long i = (long)blockIdx.x * 256 + threadIdx.x; i < n; i += 256L * 1024) {
    int d = (int)(i & 511);
    int b = (int)(i >> 9) / 196;
    float df = full[i] - vec[b * 512 + d];
    loc += (double)df * (double)df;
  }
  __shared__ double sh[256];
  sh[threadIdx.x] = loc;
  __syncthreads();
  for (int st = 128; st > 0; st >>= 1) {
    if (threadIdx.x < st) sh[threadIdx.x] += sh[threadIdx.x + st];
    __syncthreads();
  }
  if (threadIdx.x == 0) part[blockIdx.x] = sh[0];
}

__global__ void k_finloss(const double* __restrict__ part, float* __restrict__ out) {
  __shared__ double sh[256];
  double s = 0;
  for (int i = threadIdx.x; i < 4096; i += 256) s += part[i];
  sh[threadIdx.x] = s;
  __syncthreads();
  for (int st = 128; st > 0; st >>= 1) {
    if (threadIdx.x < st) sh[threadIdx.x] += sh[threadIdx.x + st];
    __syncthreads();
  }
  if (threadIdx.x == 0) out[0] = (float)(sh[0] / (64.0 * 196.0 * 512.0));
}

__global__ __launch_bounds__(256) void k_concat2(float* __restrict__ dst, const float* __restrict__ a,
                                                 const float* __restrict__ b) {
  int i = blockIdx.x * 256 + threadIdx.x;   // 64*1024
  int col = i & 1023, row = i >> 10;
  dst[i] = (col < 512) ? a[row * 512 + col] : b[row * 512 + col - 512];
}

// comb chunk: rows [r0, r0+3136) of [BS,2048] into dst
__global__ __launch_bounds__(256) void k_comb_chunk(
    float* __restrict__ dst, const float* __restrict__ d1, const float* __restrict__ d2,
    const float* __restrict__ txt, const float* __restrict__ al, long r0) {
  long i = (long)blockIdx.x * 256 + threadIdx.x;  // 3136*2048
  int col = (int)(i & 2047);
  long m = r0 + (i >> 11);
  int b = (int)(m / 196);
  float v;
  if (col < 512)       v = d1[m * 512 + col];
  else if (col < 1024) v = d2[m * 512 + col - 512];
  else if (col < 1536) v = txt[(long)b * 512 + col - 1024];
  else                 v = al[(long)b * 512 + col - 1536];
  dst[i] = v;
}

// ---------------- host ----------------
extern "C" void kernel_launch(void* const* d_in, const int* in_sizes, int n_in,
                              void* d_out, int out_size, void* d_ws, size_t ws_size,
                              hipStream_t stream) {
  (void)in_sizes; (void)n_in; (void)out_size; (void)ws_size;
  const float* in1    = (const float*)d_in[0];
  const float* in2    = (const float*)d_in[1];
  const float* cap1   = (const float*)d_in[2];
  const float* cap2   = (const float*)d_in[3];
  const float* imgw   = (const float*)d_in[4];
  const float* imgb   = (const float*)d_in[5];
  const float* wemb   = (const float*)d_in[6];
  const float* hemb   = (const float*)d_in[7];
  const float* mlpw1  = (const float*)d_in[8];
  const float* mlpb1  = (const float*)d_in[9];
  const float* mlpw2  = (const float*)d_in[10];
  const float* mlpb2  = (const float*)d_in[11];
  const float* fcw    = (const float*)d_in[12];
  const float* fcb    = (const float*)d_in[13];
  const float* efcw   = (const float*)d_in[14];
  const float* efcb   = (const float*)d_in[15];
  const float* efc2w  = (const float*)d_in[16];
  const float* efc2b  = (const float*)d_in[17];
  const float* trinw  = (const float*)d_in[18];
  const float* trinb  = (const float*)d_in[19];
  const float* troutw = (const float*)d_in[20];
  const float* troutb = (const float*)d_in[21];
  const float* trlng  = (const float*)d_in[22];
  const float* trlnb  = (const float*)d_in[23];
  const float* itqw = (const float*)d_in[24]; const float* itqb = (const float*)d_in[25];
  const float* itkw = (const float*)d_in[26]; const float* itkb = (const float*)d_in[27];
  const float* itvw = (const float*)d_in[28]; const float* itvb = (const float*)d_in[29];
  const float* caqw = (const float*)d_in[30]; const float* caqb = (const float*)d_in[31];
  const float* cakw = (const float*)d_in[32]; const float* cakb = (const float*)d_in[33];
  const float* cavw = (const float*)d_in[34]; const float* cavb = (const float*)d_in[35];
  const float* saqw = (const float*)d_in[36]; const float* saqb = (const float*)d_in[37];
  const float* sakw = (const float*)d_in[38]; const float* sakb = (const float*)d_in[39];
  const float* savw = (const float*)d_in[40]; const float* savb = (const float*)d_in[41];

  float* out = (float*)d_out;

  // ---- workspace carve (~185 MB total) ----
  const size_t SZ = (size_t)BS * 512;        // 6,422,528 floats (24.5 MB)
  float* w = (float*)d_ws;
  auto alloc = [&](size_t n) { float* p = w; w += n; return p; };
  float* h1 = alloc(SZ);
  float* h2 = alloc(SZ);
  float* tA = alloc(SZ);
  float* tB = alloc(SZ);
  float* tC = alloc(SZ);
  float* tD = alloc(SZ);
  float* sbuf = alloc((size_t)128 * 196 * 208);  // 5.2M floats: attention scores
  float* cap1o = alloc(64 * 16 * 512);
  float* cap2o = alloc(64 * 16 * 512);
  float* qc1   = alloc(64 * 16 * 512);
  float* qc2   = alloc(64 * 16 * 512);
  float* attb  = alloc(64 * 16 * 512);
  float* cmat  = alloc(512 * 512);
  float* colsum1 = alloc(512); float* colsq1 = alloc(512);
  float* colsum2 = alloc(512); float* colsq2 = alloc(512);
  float* mean1 = alloc(512); float* istd1 = alloc(512);
  float* mean2 = alloc(512); float* istd2 = alloc(512);
  float* mask1 = alloc(1024); float* mask2 = alloc(1024);
  float* vdbef = alloc(64 * 512); float* vdaft = alloc(64 * 512);
  float* vsbef = alloc(64 * 512); float* vsaft = alloc(64 * 512);
  float* cm1 = alloc(64 * 512); float* cm2 = alloc(64 * 512);
  float* vdyn = alloc(64 * 512); float* vsta = alloc(64 * 512);
  float* valign = alloc(64 * 512); float* vtxt = alloc(64 * 512);
  float* ccat = alloc(64 * 1024);
  double* msepart = (double*)alloc(4096 * 2);  // 4096 doubles

  auto gemm = [&](const float* Aa, const float* Ww, const float* bb, float* Cc,
                  int M, int N, int K, int relu) {
    k_gemm_nt<<<dim3(N / 64, M / 64), dim3(16, 16), 0, stream>>>(Aa, Ww, bb, Cc, M, N, K, relu);
  };
  auto embed = [&](const float* X, const float* sub, float* Cc) {
    k_gemm_embed<<<dim3(8, BS / 64), dim3(16, 16), 0, stream>>>(X, imgw, imgb, wemb, hemb, sub, Cc);
  };
  const int64_t RB = (int64_t)SS * 512;   // 100352
  const int64_t QB = 16 * 512;            // 8192
  const int64_t ZS = (int64_t)196 * 208;  // scores per (b,h)
  // GEMM-ized attention for D=512 single-head cases (ECA: M=196, ITDA: M=16)
  auto attn512 = [&](const float* Qp, const float* Kp, const float* Vp, float* Op,
                     int M, int64_t qZ, int64_t oZ, float scale) {
    int mt = (M + 63) / 64;
    int64_t sS = (int64_t)M * 208;
    k_bgemm_nt<<<dim3(4, mt, 64), dim3(16, 16), 0, stream>>>(
        Qp, Kp, sbuf, M, 196, 512, 512, 512, 208, 1,
        qZ, 0, RB, 0, sS, 0, scale, 1);
    k_softmax_rows<<<(64 * M + 3) / 4, 256, 0, stream>>>(sbuf, 64 * M);
    k_bgemm_nn<<<dim3(8, mt, 64), dim3(16, 16), 0, stream>>>(
        sbuf, Vp, Op, M, 512, 208, 196, 208, 512, 512, 1,
        sS, 0, RB, 0, oZ, 0);
  };
  // GEMM-ized MHA attention: D=64, H=8, chunked 16 batches at a time.
  auto attn_mha = [&](const float* Qp, const float* Kp, const float* Vp, float* Op) {
    for (int cb = 0; cb < 4; ++cb) {
      const float* Qb = Qp + (size_t)cb * 16 * RB;
      const float* Kb = Kp + (size_t)cb * 16 * RB;
      const float* Vb = Vp + (size_t)cb * 16 * RB;
      float* Ob = Op + (size_t)cb * 16 * RB;
      k_bgemm_nt<<<dim3(4, 4, 128), dim3(16, 16), 0, stream>>>(
          Qb, Kb, sbuf, 196, 196, 64, 512, 512, 208, 8,
          RB, 64, RB, 64, ZS * 8, ZS, 0.125f, 0);
      k_softmax_rows<<<6272, 256, 0, stream>>>(sbuf, 25088);
      k_bgemm_nn<<<dim3(1, 4, 128), dim3(16, 16), 0, stream>>>(
          sbuf, Vb, Ob, 196, 64, 208, 196, 208, 512, 512, 8,
          ZS * 8, ZS, RB, 64, RB, 64);
    }
  };

  const float scalE = 1.0f / sqrtf(512.0f);

  // ---- Phase 1: embed (h starts as x) + caption projections ----
  embed(in1, nullptr, h1);
  embed(in2, nullptr, h2);
  gemm(cap1, fcw, fcb, cap1o, 1024, 512, 768, 0);
  gemm(cap2, fcw, fcb, cap2o, 1024, 512, 768, 0);
  k_meannc<<<dim3(2, 64), 256, 0, stream>>>(cap1o, nullptr, cm1);
  k_meannc<<<dim3(2, 64), 256, 0, stream>>>(cap2o, nullptr, cm2);

  // ---- Phase 2: CDCR loss (f1->tA, f2->tB, hidden chunk in tC) ----
  for (int c = 0; c < 4; ++c) {
    const size_t off = (size_t)c * 3136 * 512;
    gemm(h1 + off, mlpw1, mlpb1, tC, 3136, 2048, 512, 1);
    gemm(tC, mlpw2, mlpb2, tA + off, 3136, 512, 2048, 0);
  }
  for (int c = 0; c < 4; ++c) {
    const size_t off = (size_t)c * 3136 * 512;
    gemm(h2 + off, mlpw1, mlpb1, tC, 3136, 2048, 512, 1);
    gemm(tC, mlpw2, mlpb2, tB + off, 3136, 512, 2048, 0);
  }
  k_zero<<<8, 256, 0, stream>>>(colsum1, 2048);  // colsum1..colsq2 contiguous
  k_colstats<<<dim3(16, 49), 256, 0, stream>>>(tA, colsum1, colsq1);
  k_colstats<<<dim3(16, 49), 256, 0, stream>>>(tB, colsum2, colsq2);
  k_finstats<<<2, 256, 0, stream>>>(colsum1, colsq1, mean1, istd1);
  k_finstats<<<2, 256, 0, stream>>>(colsum2, colsq2, mean2, istd2);
  k_znorm<<<25088, 256, 0, stream>>>(tA, mean1, istd1);
  k_znorm<<<25088, 256, 0, stream>>>(tB, mean2, istd2);
  k_zero<<<1024, 256, 0, stream>>>(cmat, 262144);
  k_corr<<<dim3(8, 8, 8), dim3(16, 16), 0, stream>>>(tA, tB, cmat, BS / 8, 1.0f / (float)BS);
  k_cdcr<<<1, 256, 0, stream>>>(cmat, out + NOUT);

  // ---- Phase 3: cross-transformer (2 layers, simultaneous update) ----
  for (int l = 0; l < 2; ++l) {
    const float* Wq = trinw + (size_t)l * 1536 * 512;
    const float* Wk = Wq + 512 * 512;
    const float* Wv = Wq + 2 * 512 * 512;
    const float* bq = trinb + l * 1536;
    const float* bk = bq + 512;
    const float* bv = bq + 1024;
    const float* Wo = troutw + (size_t)l * 512 * 512;
    const float* bo = troutb + l * 512;
    const float* g  = trlng + l * 512;
    const float* be = trlnb + l * 512;
    // dir1: q=h1, kv=h2
    gemm(h1, Wq, bq, tA, BS, 512, 512, 0);
    gemm(h2, Wk, bk, tB, BS, 512, 512, 0);
    gemm(h2, Wv, bv, tC, BS, 512, 512, 0);
    attn_mha(tA, tB, tC, tA);
    gemm(tA, Wo, bo, tD, BS, 512, 512, 0);       // o1 -> tD
    // dir2 projections from ORIGINAL h1,h2
    gemm(h2, Wq, bq, tA, BS, 512, 512, 0);
    gemm(h1, Wk, bk, tB, BS, 512, 512, 0);
    gemm(h1, Wv, bv, tC, BS, 512, 512, 0);
    k_addln<<<BS, 256, 0, stream>>>(h1, tD, g, be);  // h1 consumed above; update now
    attn_mha(tA, tB, tC, tA);
    gemm(tA, Wo, bo, tD, BS, 512, 512, 0);       // o2 -> tD
    k_addln<<<BS, 256, 0, stream>>>(h2, tD, g, be);
  }

  // ---- Phase 4: diffs via embed recompute (deterministic, bitwise-equal x) ----
  embed(in1, h1, tC);   // diff1 = x1 - h1
  embed(in2, h2, tD);   // diff2 = x2 - h2
  // h1, h2 now free

  // ---- Phase 5: ITDA (queries constant over S -> per-(b,nc) attention + masked mean) ----
  gemm(cap1o, itqw, itqb, qc1, 1024, 512, 512, 0);
  gemm(cap2o, itqw, itqb, qc2, 1024, 512, 512, 0);
  k_mask<<<1024, 64, 0, stream>>>(cap1o, mask1);
  k_mask<<<1024, 64, 0, stream>>>(cap2o, mask2);
  // K1,V1 from diff1
  gemm(tC, itkw, itkb, tA, BS, 512, 512, 0);
  gemm(tC, itvw, itvb, tB, BS, 512, 512, 0);
  attn512(qc2, tA, tB, attb, 16, QB, QB, scalE);
  k_meannc<<<dim3(2, 64), 256, 0, stream>>>(attb, mask2, vdbef);   // d_bef
  attn512(qc1, tA, tB, attb, 16, QB, QB, scalE);
  k_meannc<<<dim3(2, 64), 256, 0, stream>>>(attb, mask1, vsbef);   // s_bef
  // K2,V2 from diff2
  gemm(tD, itkw, itkb, tA, BS, 512, 512, 0);
  gemm(tD, itvw, itvb, tB, BS, 512, 512, 0);
  attn512(qc1, tA, tB, attb, 16, QB, QB, scalE);
  k_meannc<<<dim3(2, 64), 256, 0, stream>>>(attb, mask1, vdaft);   // d_aft
  attn512(qc2, tA, tB, attb, 16, QB, QB, scalE);
  k_meannc<<<dim3(2, 64), 256, 0, stream>>>(attb, mask2, vsaft);   // s_aft

  // ---- Phase 6: ECA x4 with immediate MSE vs ITDA vector ----
  auto eca_mse = [&](const float* xq, const float* xkv,
                     const float* qw2, const float* qb2, const float* kw2, const float* kb2,
                     const float* vw2, const float* vb2, const float* vec, double* part) {
    gemm(xq,  qw2, qb2, tA, BS, 512, 512, 0);
    gemm(xkv, kw2, kb2, tB, BS, 512, 512, 0);
    gemm(xkv, vw2, vb2, h1, BS, 512, 512, 0);
    attn512(tA, tB, h1, tA, 196, RB, RB, scalE);
    k_mse<<<1024, 256, 0, stream>>>(tA, vec, part);
  };
  eca_mse(tC, tD, caqw, caqb, cakw, cakb, cavw, cavb, vdbef, msepart);          // c12 vs d_bef
  eca_mse(tD, tC, caqw, caqb, cakw, cakb, cavw, cavb, vdaft, msepart + 1024);   // c21 vs d_aft
  eca_mse(tC, tC, saqw, saqb, sakw, sakb, savw, savb, vsbef, msepart + 2048);   // s11 vs s_bef
  eca_mse(tD, tD, saqw, saqb, sakw, sakb, savw, savb, vsaft, msepart + 3072);   // s22 vs s_aft
  k_finloss<<<1, 256, 0, stream>>>(msepart, out + NOUT + 1);

  // ---- Phase 7: efc chain (per-batch vectors) ----
  k_concat2<<<256, 256, 0, stream>>>(ccat, vdbef, vdaft);
  gemm(ccat, efcw, efcb, vdyn, 64, 512, 1024, 1);
  k_concat2<<<256, 256, 0, stream>>>(ccat, vsbef, vsaft);
  gemm(ccat, efcw, efcb, vsta, 64, 512, 1024, 1);
  k_concat2<<<256, 256, 0, stream>>>(ccat, vdyn, vsta);
  gemm(ccat, efcw, efcb, valign, 64, 512, 1024, 1);
  k_concat2<<<256, 256, 0, stream>>>(ccat, cm1, cm2);
  gemm(ccat, efcw, efcb, vtxt, 64, 512, 1024, 1);

  // ---- Phase 8: final projection, chunked comb (3136 rows/chunk) ----
  for (int c = 0; c < 4; ++c) {
    long r0 = (long)c * 3136;
    k_comb_chunk<<<25088, 256, 0, stream>>>(tA, tC, tD, vtxt, valign, r0);
    gemm(tA, efc2w, efc2b, out + r0 * 512, 3136, 512, 2048, 1);
  }
}

// Round 6
// 4594.484 us; speedup vs baseline: 3.6756x; 2.0352x over previous
//
#include <hip/hip_runtime.h>
#include <stdint.h>
#include <math.h>

// Problem constants
#define BB   64
#define SS   196
#define BS   12544            // BB*SS
#define NOUT 6422528L         // BS*512

typedef __attribute__((ext_vector_type(8))) short bf16x8;
typedef __attribute__((ext_vector_type(4))) float f32x4;

// ---------------- device helpers ----------------
__device__ __forceinline__ float block_red256(float v, float* red, bool ismax) {
#pragma unroll
  for (int o = 32; o > 0; o >>= 1) {
    float t = __shfl_down(v, o, 64);
    v = ismax ? fmaxf(v, t) : v + t;
  }
  int lane = threadIdx.x & 63, wid = threadIdx.x >> 6;
  if (lane == 0) red[wid] = v;
  __syncthreads();
  float r = ismax ? fmaxf(fmaxf(red[0], red[1]), fmaxf(red[2], red[3]))
                  : (red[0] + red[1]) + (red[2] + red[3]);
  __syncthreads();
  return r;
}

__device__ __forceinline__ short f2bf(float f) {
  union { float f; unsigned u; } v; v.f = f;
  unsigned r = v.u + 0x7fffu + ((v.u >> 16) & 1u);   // round-to-nearest-even
  return (short)(r >> 16);
}

__device__ __forceinline__ void cvt8(short* dst, float4 a, float4 b) {
  union { short s[8]; int4 v; } u;
  u.s[0] = f2bf(a.x); u.s[1] = f2bf(a.y); u.s[2] = f2bf(a.z); u.s[3] = f2bf(a.w);
  u.s[4] = f2bf(b.x); u.s[5] = f2bf(b.y); u.s[6] = f2bf(b.z); u.s[7] = f2bf(b.w);
  *(int4*)dst = u.v;
}

// ---- bf16 MFMA GEMM: C[M,N] = A[M,K] @ W[N,K]^T + bias (opt relu) ----
// 128x128 tile, BK=32, 4 waves (2x2), each wave 64x64 via 4x4 mfma_16x16x32.
// M%128==0, N%128==0, K%32==0 required.
__global__ __launch_bounds__(256) void k_mfma_nt(
    const float* __restrict__ A, const float* __restrict__ W,
    const float* __restrict__ bias, float* __restrict__ C,
    int M, int N, int K, int relu) {
  __shared__ short As[128][40];
  __shared__ short Bs[128][40];
  const int tid = threadIdx.x;
  const int lane = tid & 63, wave = tid >> 6;
  const int wm = wave >> 1, wn = wave & 1;
  const int m0 = blockIdx.y * 128, n0 = blockIdx.x * 128;
  const int srow = tid >> 1, skh = (tid & 1) * 16;
  const float* Ap = A + (long)(m0 + srow) * K + skh;
  const float* Wp = W + (long)(n0 + srow) * K + skh;
  const int fr = lane & 15, fq = lane >> 4;
  f32x4 acc[4][4] = {};
  for (int k0 = 0; k0 < K; k0 += 32) {
    float4 a0 = *(const float4*)(Ap + k0);
    float4 a1 = *(const float4*)(Ap + k0 + 4);
    float4 a2 = *(const float4*)(Ap + k0 + 8);
    float4 a3 = *(const float4*)(Ap + k0 + 12);
    float4 w0 = *(const float4*)(Wp + k0);
    float4 w1 = *(const float4*)(Wp + k0 + 4);
    float4 w2 = *(const float4*)(Wp + k0 + 8);
    float4 w3 = *(const float4*)(Wp + k0 + 12);
    cvt8(&As[srow][skh], a0, a1);
    cvt8(&As[srow][skh + 8], a2, a3);
    cvt8(&Bs[srow][skh], w0, w1);
    cvt8(&Bs[srow][skh + 8], w2, w3);
    __syncthreads();
    bf16x8 af[4], bfr[4];
#pragma unroll
    for (int i = 0; i < 4; ++i) af[i] = *(const bf16x8*)&As[wm * 64 + i * 16 + fr][fq * 8];
#pragma unroll
    for (int j = 0; j < 4; ++j) bfr[j] = *(const bf16x8*)&Bs[wn * 64 + j * 16 + fr][fq * 8];
#pragma unroll
    for (int i = 0; i < 4; ++i)
#pragma unroll
      for (int j = 0; j < 4; ++j)
        acc[i][j] = __builtin_amdgcn_mfma_f32_16x16x32_bf16(af[i], bfr[j], acc[i][j], 0, 0, 0);
    __syncthreads();
  }
#pragma unroll
  for (int i = 0; i < 4; ++i) {
    int mB = m0 + wm * 64 + i * 16 + fq * 4;
#pragma unroll
    for (int j = 0; j < 4; ++j) {
      int n = n0 + wn * 64 + j * 16 + fr;
      float bz = bias[n];
#pragma unroll
      for (int r2 = 0; r2 < 4; ++r2) {
        float v = acc[i][j][r2] + bz;
        if (relu) v = fmaxf(v, 0.f);
        C[(long)(mB + r2) * N + n] = v;
      }
    }
  }
}

// ---- bf16 MFMA embed: C[b,s,a] = sum_c X[b,c,s]*W[a,c] + bias + pe - sub ----
__global__ __launch_bounds__(256) void k_mfma_embed(
    const float* __restrict__ X,   // [B,1024,196]
    const float* __restrict__ W,   // [512,1024]
    const float* __restrict__ bias,
    const float* __restrict__ wemb, const float* __restrict__ hemb,
    const float* __restrict__ sub,  // nullptr or [BS,512]
    float* __restrict__ C) {        // [BS,512]
  __shared__ short As[128][40];
  __shared__ short Bs[128][40];
  const int tid = threadIdx.x;
  const int lane = tid & 63, wave = tid >> 6;
  const int wm = wave >> 1, wn = wave & 1;
  const int m0 = blockIdx.y * 128, n0 = blockIdx.x * 128;
  const int K = 1024, N = 512;
  const int srow = tid >> 1, skh = (tid & 1) * 16;
  const float* Wp = W + (long)(n0 + srow) * K + skh;
  // A staging: this thread owns row (tid&127), khalf (tid>>7)
  const int arow = tid & 127, khalf = tid >> 7;
  const int am = m0 + arow;
  const int ab = am / 196, as_ = am % 196;
  const float* Xp = X + (long)ab * 200704 + as_;
  const int fr = lane & 15, fq = lane >> 4;
  f32x4 acc[4][4] = {};
  for (int k0 = 0; k0 < K; k0 += 32) {
#pragma unroll
    for (int i = 0; i < 16; ++i) {
      int kk = 2 * i + khalf;
      As[arow][kk] = f2bf(Xp[(long)(k0 + kk) * 196]);
    }
    float4 w0 = *(const float4*)(Wp + k0);
    float4 w1 = *(const float4*)(Wp + k0 + 4);
    float4 w2 = *(const float4*)(Wp + k0 + 8);
    float4 w3 = *(const float4*)(Wp + k0 + 12);
    cvt8(&Bs[srow][skh], w0, w1);
    cvt8(&Bs[srow][skh + 8], w2, w3);
    __syncthreads();
    bf16x8 af[4], bfr[4];
#pragma unroll
    for (int i = 0; i < 4; ++i) af[i] = *(const bf16x8*)&As[wm * 64 + i * 16 + fr][fq * 8];
#pragma unroll
    for (int j = 0; j < 4; ++j) bfr[j] = *(const bf16x8*)&Bs[wn * 64 + j * 16 + fr][fq * 8];
#pragma unroll
    for (int i = 0; i < 4; ++i)
#pragma unroll
      for (int j = 0; j < 4; ++j)
        acc[i][j] = __builtin_amdgcn_mfma_f32_16x16x32_bf16(af[i], bfr[j], acc[i][j], 0, 0, 0);
    __syncthreads();
  }
#pragma unroll
  for (int i = 0; i < 4; ++i) {
    int mB = m0 + wm * 64 + i * 16 + fq * 4;
#pragma unroll
    for (int j = 0; j < 4; ++j) {
      int n = n0 + wn * 64 + j * 16 + fr;
      float bz = bias[n];
#pragma unroll
      for (int r2 = 0; r2 < 4; ++r2) {
        int m = mB + r2;
        int s = m % 196;
        float pe = (n < 256) ? wemb[(s % 14) * 256 + n] : hemb[(s / 14) * 256 + (n - 256)];
        float v = acc[i][j][r2] + bz + pe;
        if (sub) v -= sub[(long)m * N + n];
        C[(long)m * N + n] = v;
      }
    }
  }
}

// ---------------- fp32 GEMM fallback (M or N not 128-aligned) ----------------
__global__ __launch_bounds__(256) void k_gemm_nt(
    const float* __restrict__ A, const float* __restrict__ W,
    const float* __restrict__ bias, float* __restrict__ C,
    int M, int N, int K, int relu) {
  __shared__ float As[16][68];
  __shared__ float Ws[16][68];
  const int tx = threadIdx.x, ty = threadIdx.y;
  const int tid = ty * 16 + tx;
  const int m0 = blockIdx.y * 64, n0 = blockIdx.x * 64;
  const int lr = tid >> 2, lk = (tid & 3) << 2;
  const float* Ap = A + (long)(m0 + lr) * K + lk;
  const float* Wp = W + (long)(n0 + lr) * K + lk;
  float acc[4][4] = {};
  for (int k0 = 0; k0 < K; k0 += 16) {
    float4 av = *(const float4*)(Ap + k0);
    float4 wv = *(const float4*)(Wp + k0);
    As[lk + 0][lr] = av.x; As[lk + 1][lr] = av.y; As[lk + 2][lr] = av.z; As[lk + 3][lr] = av.w;
    Ws[lk + 0][lr] = wv.x; Ws[lk + 1][lr] = wv.y; Ws[lk + 2][lr] = wv.z; Ws[lk + 3][lr] = wv.w;
    __syncthreads();
#pragma unroll
    for (int kk = 0; kk < 16; ++kk) {
      float4 a4 = *(const float4*)&As[kk][ty * 4];
      float4 w4 = *(const float4*)&Ws[kk][tx * 4];
      float a[4] = {a4.x, a4.y, a4.z, a4.w};
      float w[4] = {w4.x, w4.y, w4.z, w4.w};
#pragma unroll
      for (int i = 0; i < 4; ++i)
#pragma unroll
        for (int j = 0; j < 4; ++j) acc[i][j] += a[i] * w[j];
    }
    __syncthreads();
  }
#pragma unroll
  for (int i = 0; i < 4; ++i) {
    int m = m0 + ty * 4 + i;
#pragma unroll
    for (int j = 0; j < 4; ++j) {
      int n = n0 + tx * 4 + j;
      float v = acc[i][j] + bias[n];
      if (relu) v = fmaxf(v, 0.f);
      C[(long)m * N + n] = v;
    }
  }
}

// ---- Batched NT GEMM: C[z][m,n] = scale * sum_k A[z][m,k]*B[z][n,k], opt clamp ----
__global__ __launch_bounds__(256) void k_bgemm_nt(
    const float* __restrict__ A, const float* __restrict__ B, float* __restrict__ C,
    int M, int N, int K, int lda, int ldb, int ldc, int nz2,
    int64_t sA1, int64_t sA2, int64_t sB1, int64_t sB2, int64_t sC1, int64_t sC2,
    float scale, int clampf) {
  __shared__ float As[16][68];
  __shared__ float Bs[16][68];
  const int tx = threadIdx.x, ty = threadIdx.y;
  const int tid = ty * 16 + tx;
  const int m0 = blockIdx.y * 64, n0 = blockIdx.x * 64;
  const int z = blockIdx.z;
  const int z1 = z / nz2, z2 = z % nz2;
  const float* Ab = A + z1 * sA1 + z2 * sA2;
  const float* Bb = B + z1 * sB1 + z2 * sB2;
  float* Cb = C + z1 * sC1 + z2 * sC2;
  const int lr = tid >> 2, lk = (tid & 3) << 2;
  const int ar = (m0 + lr < M) ? m0 + lr : M - 1;
  const int br = (n0 + lr < N) ? n0 + lr : N - 1;
  const float* Ap = Ab + (long)ar * lda + lk;
  const float* Bp = Bb + (long)br * ldb + lk;
  float acc[4][4] = {};
  for (int k0 = 0; k0 < K; k0 += 16) {
    float4 av = *(const float4*)(Ap + k0);
    float4 bv = *(const float4*)(Bp + k0);
    As[lk + 0][lr] = av.x; As[lk + 1][lr] = av.y; As[lk + 2][lr] = av.z; As[lk + 3][lr] = av.w;
    Bs[lk + 0][lr] = bv.x; Bs[lk + 1][lr] = bv.y; Bs[lk + 2][lr] = bv.z; Bs[lk + 3][lr] = bv.w;
    __syncthreads();
#pragma unroll
    for (int kk = 0; kk < 16; ++kk) {
      float4 a4 = *(const float4*)&As[kk][ty * 4];
      float4 b4 = *(const float4*)&Bs[kk][tx * 4];
      float a[4] = {a4.x, a4.y, a4.z, a4.w};
      float b[4] = {b4.x, b4.y, b4.z, b4.w};
#pragma unroll
      for (int i = 0; i < 4; ++i)
#pragma unroll
        for (int j = 0; j < 4; ++j) acc[i][j] += a[i] * b[j];
    }
    __syncthreads();
  }
#pragma unroll
  for (int i = 0; i < 4; ++i) {
    int m = m0 + ty * 4 + i;
    if (m >= M) continue;
#pragma unroll
    for (int j = 0; j < 4; ++j) {
      int n = n0 + tx * 4 + j;
      if (n >= N) continue;
      float v = acc[i][j] * scale;
      if (clampf) v = fminf(fmaxf(v, -100.f), 100.f);
      Cb[(long)m * ldc + n] = v;
    }
  }
}

// ---- Batched NN GEMM: C[z][m,n] = sum_k A[z][m,k]*B[z][k,n]. ----
__global__ __launch_bounds__(256) void k_bgemm_nn(
    const float* __restrict__ A, const float* __restrict__ B, float* __restrict__ C,
    int M, int N, int K, int KBvalid, int lda, int ldb, int ldc, int nz2,
    int64_t sA1, int64_t sA2, int64_t sB1, int64_t sB2, int64_t sC1, int64_t sC2) {
  __shared__ float As[16][68];
  __shared__ float Bs[16][68];
  const int tx = threadIdx.x, ty = threadIdx.y;
  const int tid = ty * 16 + tx;
  const int m0 = blockIdx.y * 64, n0 = blockIdx.x * 64;
  const int z = blockIdx.z;
  const int z1 = z / nz2, z2 = z % nz2;
  const float* Ab = A + z1 * sA1 + z2 * sA2;
  const float* Bb = B + z1 * sB1 + z2 * sB2;
  float* Cb = C + z1 * sC1 + z2 * sC2;
  const int lr = tid >> 2, lk = (tid & 3) << 2;
  const int ar = (m0 + lr < M) ? m0 + lr : M - 1;
  const float* Ap = Ab + (long)ar * lda + lk;
  const int bk = tid >> 6, bn = tid & 63;
  float acc[4][4] = {};
  for (int k0 = 0; k0 < K; k0 += 16) {
    float4 av = *(const float4*)(Ap + k0);
    As[lk + 0][lr] = av.x; As[lk + 1][lr] = av.y; As[lk + 2][lr] = av.z; As[lk + 3][lr] = av.w;
#pragma unroll
    for (int kko = 0; kko < 16; kko += 4) {
      int k = k0 + bk + kko;
      int kc = (k < KBvalid) ? k : KBvalid - 1;
      Bs[bk + kko][bn] = Bb[(long)kc * ldb + n0 + bn];
    }
    __syncthreads();
#pragma unroll
    for (int kk = 0; kk < 16; ++kk) {
      float4 a4 = *(const float4*)&As[kk][ty * 4];
      float4 b4 = *(const float4*)&Bs[kk][tx * 4];
      float a[4] = {a4.x, a4.y, a4.z, a4.w};
      float b[4] = {b4.x, b4.y, b4.z, b4.w};
#pragma unroll
      for (int i = 0; i < 4; ++i)
#pragma unroll
        for (int j = 0; j < 4; ++j) acc[i][j] += a[i] * b[j];
    }
    __syncthreads();
  }
#pragma unroll
  for (int i = 0; i < 4; ++i) {
    int m = m0 + ty * 4 + i;
    if (m >= M) continue;
#pragma unroll
    for (int j = 0; j < 4; ++j) {
      int n = n0 + tx * 4 + j;
      if (n >= N) continue;
      Cb[(long)m * ldc + n] = acc[i][j];
    }
  }
}

// ---- Row softmax over rows of width 196, ld=208; zeroes pad cols. 1 wave/row. ----
__global__ __launch_bounds__(256) void k_softmax_rows(float* __restrict__ S, int nrows) {
  int row = blockIdx.x * 4 + (threadIdx.x >> 6);
  int lane = threadIdx.x & 63;
  if (row >= nrows) return;
  float* p = S + (long)row * 208;
  float v0 = p[lane];
  float v1 = p[lane + 64];
  float v2 = p[lane + 128];
  float v3 = (lane + 192 < 196) ? p[lane + 192] : -1e30f;
  float mx = fmaxf(fmaxf(v0, v1), fmaxf(v2, v3));
#pragma unroll
  for (int o = 32; o > 0; o >>= 1) mx = fmaxf(mx, __shfl_down(mx, o, 64));
  mx = __shfl(mx, 0, 64);
  float e0 = expf(v0 - mx), e1 = expf(v1 - mx), e2 = expf(v2 - mx);
  float e3 = (lane + 192 < 196) ? expf(v3 - mx) : 0.f;
  float s = e0 + e1 + e2 + e3;
#pragma unroll
  for (int o = 32; o > 0; o >>= 1) s += __shfl_down(s, o, 64);
  s = __shfl(s, 0, 64);
  float inv = 1.0f / s;
  p[lane] = e0 * inv;
  p[lane + 64] = e1 * inv;
  p[lane + 128] = e2 * inv;
  if (lane + 192 < 208) p[lane + 192] = (lane + 192 < 196) ? e3 * inv : 0.f;
}

// ---- Correlation: C[i,j] += scale * sum_m Za[m,i]*Zb[m,j] (split-K atomic) ----
__global__ __launch_bounds__(256) void k_corr(
    const float* __restrict__ Za, const float* __restrict__ Zb,
    float* __restrict__ C, int mchunk, float scale) {
  __shared__ float As[16][68];
  __shared__ float Bs[16][68];
  const int tx = threadIdx.x, ty = threadIdx.y;
  const int tid = ty * 16 + tx;
  const int i0 = blockIdx.y * 64, j0 = blockIdx.x * 64;
  const int li = (tid & 15) * 4, lm = tid >> 4;
  float acc[4][4] = {};
  const int mstart = blockIdx.z * mchunk;
  for (int m0 = mstart; m0 < mstart + mchunk; m0 += 16) {
    *(float4*)&As[lm][li] = *(const float4*)(Za + (long)(m0 + lm) * 512 + i0 + li);
    *(float4*)&Bs[lm][li] = *(const float4*)(Zb + (long)(m0 + lm) * 512 + j0 + li);
    __syncthreads();
#pragma unroll
    for (int mm = 0; mm < 16; ++mm) {
      float4 a4 = *(const float4*)&As[mm][ty * 4];
      float4 b4 = *(const float4*)&Bs[mm][tx * 4];
      float a[4] = {a4.x, a4.y, a4.z, a4.w};
      float b[4] = {b4.x, b4.y, b4.z, b4.w};
#pragma unroll
      for (int i = 0; i < 4; ++i)
#pragma unroll
        for (int j = 0; j < 4; ++j) acc[i][j] += a[i] * b[j];
    }
    __syncthreads();
  }
#pragma unroll
  for (int i = 0; i < 4; ++i)
#pragma unroll
    for (int j = 0; j < 4; ++j)
      atomicAdd(&C[(long)(i0 + ty * 4 + i) * 512 + j0 + tx * 4 + j], acc[i][j] * scale);
}

// ---- Residual + LayerNorm (in place into h) ----
__global__ __launch_bounds__(256) void k_addln(
    float* __restrict__ h, const float* __restrict__ o,
    const float* __restrict__ g, const float* __restrict__ be) {
  __shared__ float red[4];
  long row = blockIdx.x;
  float* hr = h + row * 512;
  const float* orow = o + row * 512;
  int t = threadIdx.x;
  float v0 = hr[t] + orow[t];
  float v1 = hr[t + 256] + orow[t + 256];
  float mean = block_red256(v0 + v1, red, false) * (1.0f / 512.0f);
  float d0 = v0 - mean, d1 = v1 - mean;
  float var = block_red256(d0 * d0 + d1 * d1, red, false) * (1.0f / 512.0f);
  float inv = 1.0f / sqrtf(var + 1e-5f);
  hr[t] = d0 * inv * g[t] + be[t];
  hr[t + 256] = d1 * inv * g[t + 256] + be[t + 256];
}

// ---- small utility kernels ----
__global__ void k_zero(float* __restrict__ p, int n) {
  int i = blockIdx.x * 256 + threadIdx.x;
  if (i < n) p[i] = 0.f;
}

__global__ __launch_bounds__(256) void k_colstats(
    const float* __restrict__ f, float* __restrict__ sums, float* __restrict__ sqs) {
  int c = blockIdx.x * 32 + (threadIdx.x & 31);
  int rbase = blockIdx.y * 256;
  int r0 = rbase + (threadIdx.x >> 5);
  float s = 0.f, s2 = 0.f;
  for (int r = r0; r < rbase + 256; r += 8) {
    float v = f[(long)r * 512 + c];
    s += v; s2 += v * v;
  }
  __shared__ float sh[256], sh2[256];
  sh[threadIdx.x] = s; sh2[threadIdx.x] = s2;
  __syncthreads();
  if (threadIdx.x < 32) {
    for (int i = 1; i < 8; ++i) { s += sh[i * 32 + threadIdx.x]; s2 += sh2[i * 32 + threadIdx.x]; }
    atomicAdd(&sums[c], s);
    atomicAdd(&sqs[c], s2);
  }
}

__global__ void k_finstats(const float* __restrict__ sums, const float* __restrict__ sqs,
                           float* __restrict__ mean, float* __restrict__ istd) {
  int c = blockIdx.x * 256 + threadIdx.x;
  float mu = sums[c] / 12544.0f;
  float var = (sqs[c] - 12544.0f * mu * mu) / 12543.0f;
  mean[c] = mu;
  istd[c] = 1.0f / sqrtf(var);
}

__global__ __launch_bounds__(256) void k_znorm(float* __restrict__ f, const float* __restrict__ mean,
                                               const float* __restrict__ istd) {
  long i = (long)blockIdx.x * 256 + threadIdx.x;
  int c = (int)(i & 511);
  f[i] = (f[i] - mean[c]) * istd[c];
}

// CDCR loss: 256-block partial reduce + final combine
__global__ __launch_bounds__(256) void k_cdcr_part(const float* __restrict__ Cm,
                                                   double* __restrict__ part) {
  int base = blockIdx.x * 1024;
  double on = 0, off = 0;
  for (int i = base + threadIdx.x; i < base + 1024; i += 256) {
    float v = Cm[i];
    int r = i >> 9, c = i & 511;
    if (r == c) { double d = (double)v - 1.0; on += d * d; }
    else        { off += (double)v * (double)v; }
  }
  __shared__ double s_on[256], s_off[256];
  s_on[threadIdx.x] = on; s_off[threadIdx.x] = off;
  __syncthreads();
  for (int st = 128; st > 0; st >>= 1) {
    if (threadIdx.x < st) { s_on[threadIdx.x] += s_on[threadIdx.x + st]; s_off[threadIdx.x] += s_off[threadIdx.x + st]; }
    __syncthreads();
  }
  if (threadIdx.x == 0) { part[blockIdx.x] = s_on[0]; part[256 + blockIdx.x] = s_off[0]; }
}

__global__ void k_cdcr_fin(const double* __restrict__ part, float* __restrict__ out) {
  __shared__ double s_on[256], s_off[256];
  s_on[threadIdx.x] = part[threadIdx.x];
  s_off[threadIdx.x] = part[256 + threadIdx.x];
  __syncthreads();
  for (int st = 128; st > 0; st >>= 1) {
    if (threadIdx.x < st) { s_on[threadIdx.x] += s_on[threadIdx.x + st]; s_off[threadIdx.x] += s_off[threadIdx.x + st]; }
    __syncthreads();
  }
  if (threadIdx.x == 0) out[0] = (float)(s_on[0] + 0.003 * s_off[0]);
}

__global__ __launch_bounds__(64) void k_mask(const float* __restrict__ capo, float* __restrict__ mask) {
  int pidx = blockIdx.x;
  float s = 0.f;
  for (int i = threadIdx.x; i < 512; i += 64) s += capo[(long)pidx * 512 + i];
#pragma unroll
  for (int o = 32; o > 0; o >>= 1) s += __shfl_down(s, o, 64);
  if (threadIdx.x == 0) mask[pidx] = (s != 0.f) ? 1.f : 0.f;
}

__global__ __launch_bounds__(256) void k_meannc(const float* __restrict__ src, const float* __restrict__ mask,
                                                float* __restrict__ vec) {
  int d = blockIdx.x * 256 + threadIdx.x;
  int b = blockIdx.y;
  float acc = 0.f, ms = 0.f;
  for (int nc = 0; nc < 16; ++nc) {
    float mk = mask ? mask[b * 16 + nc] : 1.f;
    acc += src[((long)b * 16 + nc) * 512 + d] * mk;
    ms += mk;
  }
  vec[(long)b * 512 + d] = acc / fmaxf(ms, 1e-6f);
}

__global__ __launch_bounds__(256) void k_mse(const float* __restrict__ full, const float* __restrict__ vec,
                                             double* __restrict__ part) {
  double loc = 0;
  const long n = NOUT;
  for (long i = (long)blockIdx.x * 256 + threadIdx.x; i < n; i += 256L * 1024) {
    int d = (int)(i & 511);
    int b = (int)(i >> 9) / 196;
    float df = full[i] - vec[b * 512 + d];
    loc += (double)df * (double)df;
  }
  __shared__ double sh[256];
  sh[threadIdx.x] = loc;
  __syncthreads();
  for (int st = 128; st > 0; st >>= 1) {
    if (threadIdx.x < st) sh[threadIdx.x] += sh[threadIdx.x + st];
    __syncthreads();
  }
  if (threadIdx.x == 0) part[blockIdx.x] = sh[0];
}

__global__ void k_finloss(const double* __restrict__ part, float* __restrict__ out) {
  __shared__ double sh[256];
  double s = 0;
  for (int i = threadIdx.x; i < 4096; i += 256) s += part[i];
  sh[threadIdx.x] = s;
  __syncthreads();
  for (int st = 128; st > 0; st >>= 1) {
    if (threadIdx.x < st) sh[threadIdx.x] += sh[threadIdx.x + st];
    __syncthreads();
  }
  if (threadIdx.x == 0) out[0] = (float)(sh[0] / (64.0 * 196.0 * 512.0));
}

__global__ __launch_bounds__(256) void k_concat2(float* __restrict__ dst, const float* __restrict__ a,
                                                 const float* __restrict__ b) {
  int i = blockIdx.x * 256 + threadIdx.x;   // 64*1024
  int col = i & 1023, row = i >> 10;
  dst[i] = (col < 512) ? a[row * 512 + col] : b[row * 512 + col - 512];
}

// comb chunk: rows [r0, r0+6272) of [BS,2048] into dst
__global__ __launch_bounds__(256) void k_comb_chunk(
    float* __restrict__ dst, const float* __restrict__ d1, const float* __restrict__ d2,
    const float* __restrict__ txt, const float* __restrict__ al, long r0) {
  long i = (long)blockIdx.x * 256 + threadIdx.x;  // 6272*2048
  int col = (int)(i & 2047);
  long m = r0 + (i >> 11);
  int b = (int)(m / 196);
  float v;
  if (col < 512)       v = d1[m * 512 + col];
  else if (col < 1024) v = d2[m * 512 + col - 512];
  else if (col < 1536) v = txt[(long)b * 512 + col - 1024];
  else                 v = al[(long)b * 512 + col - 1536];
  dst[i] = v;
}

// ---------------- host ----------------
extern "C" void kernel_launch(void* const* d_in, const int* in_sizes, int n_in,
                              void* d_out, int out_size, void* d_ws, size_t ws_size,
                              hipStream_t stream) {
  (void)in_sizes; (void)n_in; (void)out_size; (void)ws_size;
  const float* in1    = (const float*)d_in[0];
  const float* in2    = (const float*)d_in[1];
  const float* cap1   = (const float*)d_in[2];
  const float* cap2   = (const float*)d_in[3];
  const float* imgw   = (const float*)d_in[4];
  const float* imgb   = (const float*)d_in[5];
  const float* wemb   = (const float*)d_in[6];
  const float* hemb   = (const float*)d_in[7];
  const float* mlpw1  = (const float*)d_in[8];
  const float* mlpb1  = (const float*)d_in[9];
  const float* mlpw2  = (const float*)d_in[10];
  const float* mlpb2  = (const float*)d_in[11];
  const float* fcw    = (const float*)d_in[12];
  const float* fcb    = (const float*)d_in[13];
  const float* efcw   = (const float*)d_in[14];
  const float* efcb   = (const float*)d_in[15];
  const float* efc2w  = (const float*)d_in[16];
  const float* efc2b  = (const float*)d_in[17];
  const float* trinw  = (const float*)d_in[18];
  const float* trinb  = (const float*)d_in[19];
  const float* troutw = (const float*)d_in[20];
  const float* troutb = (const float*)d_in[21];
  const float* trlng  = (const float*)d_in[22];
  const float* trlnb  = (const float*)d_in[23];
  const float* itqw = (const float*)d_in[24]; const float* itqb = (const float*)d_in[25];
  const float* itkw = (const float*)d_in[26]; const float* itkb = (const float*)d_in[27];
  const float* itvw = (const float*)d_in[28]; const float* itvb = (const float*)d_in[29];
  const float* caqw = (const float*)d_in[30]; const float* caqb = (const float*)d_in[31];
  const float* cakw = (const float*)d_in[32]; const float* cakb = (const float*)d_in[33];
  const float* cavw = (const float*)d_in[34]; const float* cavb = (const float*)d_in[35];
  const float* saqw = (const float*)d_in[36]; const float* saqb = (const float*)d_in[37];
  const float* sakw = (const float*)d_in[38]; const float* sakb = (const float*)d_in[39];
  const float* savw = (const float*)d_in[40]; const float* savb = (const float*)d_in[41];

  float* out = (float*)d_out;

  // ---- workspace carve (~185 MB total) ----
  const size_t SZ = (size_t)BS * 512;        // 6,422,528 floats (24.5 MB)
  float* w = (float*)d_ws;
  auto alloc = [&](size_t n) { float* p = w; w += n; return p; };
  float* h1 = alloc(SZ);
  float* h2 = alloc(SZ);
  float* tA = alloc(SZ);
  float* tB = alloc(SZ);
  float* tC = alloc(SZ);
  float* tD = alloc(SZ);
  float* sbuf = alloc((size_t)128 * 196 * 208);  // 5.2M floats: attention scores
  float* cap1o = alloc(64 * 16 * 512);
  float* cap2o = alloc(64 * 16 * 512);
  float* qc1   = alloc(64 * 16 * 512);
  float* qc2   = alloc(64 * 16 * 512);
  float* attb  = alloc(64 * 16 * 512);
  float* cmat  = alloc(512 * 512);
  float* colsum1 = alloc(512); float* colsq1 = alloc(512);
  float* colsum2 = alloc(512); float* colsq2 = alloc(512);
  float* mean1 = alloc(512); float* istd1 = alloc(512);
  float* mean2 = alloc(512); float* istd2 = alloc(512);
  float* mask1 = alloc(1024); float* mask2 = alloc(1024);
  float* vdbef = alloc(64 * 512); float* vdaft = alloc(64 * 512);
  float* vsbef = alloc(64 * 512); float* vsaft = alloc(64 * 512);
  float* cm1 = alloc(64 * 512); float* cm2 = alloc(64 * 512);
  float* vdyn = alloc(64 * 512); float* vsta = alloc(64 * 512);
  float* valign = alloc(64 * 512); float* vtxt = alloc(64 * 512);
  float* ccat = alloc(64 * 1024);
  double* msepart = (double*)alloc(4096 * 2);   // 4096 doubles
  double* cdcrpart = (double*)alloc(1024);      // 512 doubles

  auto gemm = [&](const float* Aa, const float* Ww, const float* bb, float* Cc,
                  int M, int N, int K, int relu) {
    if ((M % 128) == 0 && (N % 128) == 0 && (K % 32) == 0)
      k_mfma_nt<<<dim3(N / 128, M / 128), 256, 0, stream>>>(Aa, Ww, bb, Cc, M, N, K, relu);
    else
      k_gemm_nt<<<dim3(N / 64, (M + 63) / 64), dim3(16, 16), 0, stream>>>(Aa, Ww, bb, Cc, M, N, K, relu);
  };
  auto embed = [&](const float* X, const float* sub, float* Cc) {
    k_mfma_embed<<<dim3(4, BS / 128), 256, 0, stream>>>(X, imgw, imgb, wemb, hemb, sub, Cc);
  };
  const int64_t RB = (int64_t)SS * 512;   // 100352
  const int64_t QB = 16 * 512;            // 8192
  const int64_t ZS = (int64_t)196 * 208;  // scores per (b,h)
  // GEMM-ized attention for D=512 single-head cases (ECA: M=196, ITDA: M=16)
  auto attn512 = [&](const float* Qp, const float* Kp, const float* Vp, float* Op,
                     int M, int64_t qZ, int64_t oZ, float scale) {
    int mt = (M + 63) / 64;
    int64_t sS = (int64_t)M * 208;
    k_bgemm_nt<<<dim3(4, mt, 64), dim3(16, 16), 0, stream>>>(
        Qp, Kp, sbuf, M, 196, 512, 512, 512, 208, 1,
        qZ, 0, RB, 0, sS, 0, scale, 1);
    k_softmax_rows<<<(64 * M + 3) / 4, 256, 0, stream>>>(sbuf, 64 * M);
    k_bgemm_nn<<<dim3(8, mt, 64), dim3(16, 16), 0, stream>>>(
        sbuf, Vp, Op, M, 512, 208, 196, 208, 512, 512, 1,
        sS, 0, RB, 0, oZ, 0);
  };
  // GEMM-ized MHA attention: D=64, H=8, chunked 16 batches at a time.
  auto attn_mha = [&](const float* Qp, const float* Kp, const float* Vp, float* Op) {
    for (int cb = 0; cb < 4; ++cb) {
      const float* Qb = Qp + (size_t)cb * 16 * RB;
      const float* Kb = Kp + (size_t)cb * 16 * RB;
      const float* Vb = Vp + (size_t)cb * 16 * RB;
      float* Ob = Op + (size_t)cb * 16 * RB;
      k_bgemm_nt<<<dim3(4, 4, 128), dim3(16, 16), 0, stream>>>(
          Qb, Kb, sbuf, 196, 196, 64, 512, 512, 208, 8,
          RB, 64, RB, 64, ZS * 8, ZS, 0.125f, 0);
      k_softmax_rows<<<6272, 256, 0, stream>>>(sbuf, 25088);
      k_bgemm_nn<<<dim3(1, 4, 128), dim3(16, 16), 0, stream>>>(
          sbuf, Vb, Ob, 196, 64, 208, 196, 208, 512, 512, 8,
          ZS * 8, ZS, RB, 64, RB, 64);
    }
  };

  const float scalE = 1.0f / sqrtf(512.0f);

  // ---- Phase 1: embed (h starts as x) + caption projections ----
  embed(in1, nullptr, h1);
  embed(in2, nullptr, h2);
  gemm(cap1, fcw, fcb, cap1o, 1024, 512, 768, 0);
  gemm(cap2, fcw, fcb, cap2o, 1024, 512, 768, 0);
  k_meannc<<<dim3(2, 64), 256, 0, stream>>>(cap1o, nullptr, cm1);
  k_meannc<<<dim3(2, 64), 256, 0, stream>>>(cap2o, nullptr, cm2);

  // ---- Phase 2: CDCR loss (f1->tA, f2->tB, hidden chunk in tC..tD) ----
  for (int c = 0; c < 2; ++c) {
    const size_t off = (size_t)c * 6272 * 512;
    gemm(h1 + off, mlpw1, mlpb1, tC, 6272, 2048, 512, 1);
    gemm(tC, mlpw2, mlpb2, tA + off, 6272, 512, 2048, 0);
  }
  for (int c = 0; c < 2; ++c) {
    const size_t off = (size_t)c * 6272 * 512;
    gemm(h2 + off, mlpw1, mlpb1, tC, 6272, 2048, 512, 1);
    gemm(tC, mlpw2, mlpb2, tB + off, 6272, 512, 2048, 0);
  }
  k_zero<<<8, 256, 0, stream>>>(colsum1, 2048);  // colsum1..colsq2 contiguous
  k_colstats<<<dim3(16, 49), 256, 0, stream>>>(tA, colsum1, colsq1);
  k_colstats<<<dim3(16, 49), 256, 0, stream>>>(tB, colsum2, colsq2);
  k_finstats<<<2, 256, 0, stream>>>(colsum1, colsq1, mean1, istd1);
  k_finstats<<<2, 256, 0, stream>>>(colsum2, colsq2, mean2, istd2);
  k_znorm<<<25088, 256, 0, stream>>>(tA, mean1, istd1);
  k_znorm<<<25088, 256, 0, stream>>>(tB, mean2, istd2);
  k_zero<<<1024, 256, 0, stream>>>(cmat, 262144);
  k_corr<<<dim3(8, 8, 8), dim3(16, 16), 0, stream>>>(tA, tB, cmat, BS / 8, 1.0f / (float)BS);
  k_cdcr_part<<<256, 256, 0, stream>>>(cmat, cdcrpart);
  k_cdcr_fin<<<1, 256, 0, stream>>>(cdcrpart, out + NOUT);

  // ---- Phase 3: cross-transformer (2 layers, simultaneous update) ----
  for (int l = 0; l < 2; ++l) {
    const float* Wq = trinw + (size_t)l * 1536 * 512;
    const float* Wk = Wq + 512 * 512;
    const float* Wv = Wq + 2 * 512 * 512;
    const float* bq = trinb + l * 1536;
    const float* bk = bq + 512;
    const float* bv = bq + 1024;
    const float* Wo = troutw + (size_t)l * 512 * 512;
    const float* bo = troutb + l * 512;
    const float* g  = trlng + l * 512;
    const float* be = trlnb + l * 512;
    // dir1: q=h1, kv=h2
    gemm(h1, Wq, bq, tA, BS, 512, 512, 0);
    gemm(h2, Wk, bk, tB, BS, 512, 512, 0);
    gemm(h2, Wv, bv, tC, BS, 512, 512, 0);
    attn_mha(tA, tB, tC, tA);
    gemm(tA, Wo, bo, tD, BS, 512, 512, 0);       // o1 -> tD
    // dir2 projections from ORIGINAL h1,h2
    gemm(h2, Wq, bq, tA, BS, 512, 512, 0);
    gemm(h1, Wk, bk, tB, BS, 512, 512, 0);
    gemm(h1, Wv, bv, tC, BS, 512, 512, 0);
    k_addln<<<BS, 256, 0, stream>>>(h1, tD, g, be);  // h1 consumed above; update now
    attn_mha(tA, tB, tC, tA);
    gemm(tA, Wo, bo, tD, BS, 512, 512, 0);       // o2 -> tD
    k_addln<<<BS, 256, 0, stream>>>(h2, tD, g, be);
  }

  // ---- Phase 4: diffs via embed recompute (deterministic, bitwise-equal x) ----
  embed(in1, h1, tC);   // diff1 = x1 - h1
  embed(in2, h2, tD);   // diff2 = x2 - h2
  // h1, h2 now free

  // ---- Phase 5: ITDA (queries constant over S -> per-(b,nc) attention + masked mean) ----
  gemm(cap1o, itqw, itqb, qc1, 1024, 512, 512, 0);
  gemm(cap2o, itqw, itqb, qc2, 1024, 512, 512, 0);
  k_mask<<<1024, 64, 0, stream>>>(cap1o, mask1);
  k_mask<<<1024, 64, 0, stream>>>(cap2o, mask2);
  // K1,V1 from diff1
  gemm(tC, itkw, itkb, tA, BS, 512, 512, 0);
  gemm(tC, itvw, itvb, tB, BS, 512, 512, 0);
  attn512(qc2, tA, tB, attb, 16, QB, QB, scalE);
  k_meannc<<<dim3(2, 64), 256, 0, stream>>>(attb, mask2, vdbef);   // d_bef
  attn512(qc1, tA, tB, attb, 16, QB, QB, scalE);
  k_meannc<<<dim3(2, 64), 256, 0, stream>>>(attb, mask1, vsbef);   // s_bef
  // K2,V2 from diff2
  gemm(tD, itkw, itkb, tA, BS, 512, 512, 0);
  gemm(tD, itvw, itvb, tB, BS, 512, 512, 0);
  attn512(qc1, tA, tB, attb, 16, QB, QB, scalE);
  k_meannc<<<dim3(2, 64), 256, 0, stream>>>(attb, mask1, vdaft);   // d_aft
  attn512(qc2, tA, tB, attb, 16, QB, QB, scalE);
  k_meannc<<<dim3(2, 64), 256, 0, stream>>>(attb, mask2, vsaft);   // s_aft

  // ---- Phase 6: ECA x4 with immediate MSE vs ITDA vector ----
  auto eca_mse = [&](const float* xq, const float* xkv,
                     const float* qw2, const float* qb2, const float* kw2, const float* kb2,
                     const float* vw2, const float* vb2, const float* vec, double* part) {
    gemm(xq,  qw2, qb2, tA, BS, 512, 512, 0);
    gemm(xkv, kw2, kb2, tB, BS, 512, 512, 0);
    gemm(xkv, vw2, vb2, h1, BS, 512, 512, 0);
    attn512(tA, tB, h1, tA, 196, RB, RB, scalE);
    k_mse<<<1024, 256, 0, stream>>>(tA, vec, part);
  };
  eca_mse(tC, tD, caqw, caqb, cakw, cakb, cavw, cavb, vdbef, msepart);          // c12 vs d_bef
  eca_mse(tD, tC, caqw, caqb, cakw, cakb, cavw, cavb, vdaft, msepart + 1024);   // c21 vs d_aft
  eca_mse(tC, tC, saqw, saqb, sakw, sakb, savw, savb, vsbef, msepart + 2048);   // s11 vs s_bef
  eca_mse(tD, tD, saqw, saqb, sakw, sakb, savw, savb, vsaft, msepart + 3072);   // s22 vs s_aft
  k_finloss<<<1, 256, 0, stream>>>(msepart, out + NOUT + 1);

  // ---- Phase 7: efc chain (per-batch vectors, fp32 path M=64) ----
  k_concat2<<<256, 256, 0, stream>>>(ccat, vdbef, vdaft);
  gemm(ccat, efcw, efcb, vdyn, 64, 512, 1024, 1);
  k_concat2<<<256, 256, 0, stream>>>(ccat, vsbef, vsaft);
  gemm(ccat, efcw, efcb, vsta, 64, 512, 1024, 1);
  k_concat2<<<256, 256, 0, stream>>>(ccat, vdyn, vsta);
  gemm(ccat, efcw, efcb, valign, 64, 512, 1024, 1);
  k_concat2<<<256, 256, 0, stream>>>(ccat, cm1, cm2);
  gemm(ccat, efcw, efcb, vtxt, 64, 512, 1024, 1);

  // ---- Phase 8: final projection, chunked comb (6272 rows/chunk in tA..tB) ----
  for (int c = 0; c < 2; ++c) {
    long r0 = (long)c * 6272;
    k_comb_chunk<<<50176, 256, 0, stream>>>(tA, tC, tD, vtxt, valign, r0);
    gemm(tA, efc2w, efc2b, out + r0 * 512, 6272, 512, 2048, 1);
  }
}

// Round 7
// 3798.513 us; speedup vs baseline: 4.4458x; 1.2095x over previous
//
#include <hip/hip_runtime.h>
#include <stdint.h>
#include <math.h>

// Problem constants
#define BB   64
#define SS   196
#define BS   12544            // BB*SS
#define NOUT 6422528L         // BS*512
#define SLD  224              // score row ld (7*32)

typedef __attribute__((ext_vector_type(8))) short bf16x8;
typedef __attribute__((ext_vector_type(4))) float f32x4;

// ---------------- device helpers ----------------
__device__ __forceinline__ float block_red256(float v, float* red, bool ismax) {
#pragma unroll
  for (int o = 32; o > 0; o >>= 1) {
    float t = __shfl_down(v, o, 64);
    v = ismax ? fmaxf(v, t) : v + t;
  }
  int lane = threadIdx.x & 63, wid = threadIdx.x >> 6;
  if (lane == 0) red[wid] = v;
  __syncthreads();
  float r = ismax ? fmaxf(fmaxf(red[0], red[1]), fmaxf(red[2], red[3]))
                  : (red[0] + red[1]) + (red[2] + red[3]);
  __syncthreads();
  return r;
}

__device__ __forceinline__ short f2bf(float f) {
  union { float f; unsigned u; } v; v.f = f;
  unsigned r = v.u + 0x7fffu + ((v.u >> 16) & 1u);   // round-to-nearest-even
  return (short)(r >> 16);
}

__device__ __forceinline__ void cvt8(short* dst, float4 a, float4 b) {
  union { short s[8]; int4 v; } u;
  u.s[0] = f2bf(a.x); u.s[1] = f2bf(a.y); u.s[2] = f2bf(a.z); u.s[3] = f2bf(a.w);
  u.s[4] = f2bf(b.x); u.s[5] = f2bf(b.y); u.s[6] = f2bf(b.z); u.s[7] = f2bf(b.w);
  *(int4*)dst = u.v;
}

// ---- bf16 MFMA GEMM: C[M,N] = A[M,K] @ W[N,K]^T + bias (opt relu) ----
// 128x128 tile, BK=32, 4 waves (2x2). M%128==0, N%128==0, K%32==0.
__global__ __launch_bounds__(256) void k_mfma_nt(
    const float* __restrict__ A, const float* __restrict__ W,
    const float* __restrict__ bias, float* __restrict__ C,
    int M, int N, int K, int relu) {
  __shared__ short As[128][40];
  __shared__ short Bs[128][40];
  const int tid = threadIdx.x;
  const int lane = tid & 63, wave = tid >> 6;
  const int wm = wave >> 1, wn = wave & 1;
  const int m0 = blockIdx.y * 128, n0 = blockIdx.x * 128;
  const int srow = tid >> 1, skh = (tid & 1) * 16;
  const float* Ap = A + (long)(m0 + srow) * K + skh;
  const float* Wp = W + (long)(n0 + srow) * K + skh;
  const int fr = lane & 15, fq = lane >> 4;
  f32x4 acc[4][4] = {};
  for (int k0 = 0; k0 < K; k0 += 32) {
    float4 a0 = *(const float4*)(Ap + k0);
    float4 a1 = *(const float4*)(Ap + k0 + 4);
    float4 a2 = *(const float4*)(Ap + k0 + 8);
    float4 a3 = *(const float4*)(Ap + k0 + 12);
    float4 w0 = *(const float4*)(Wp + k0);
    float4 w1 = *(const float4*)(Wp + k0 + 4);
    float4 w2 = *(const float4*)(Wp + k0 + 8);
    float4 w3 = *(const float4*)(Wp + k0 + 12);
    cvt8(&As[srow][skh], a0, a1);
    cvt8(&As[srow][skh + 8], a2, a3);
    cvt8(&Bs[srow][skh], w0, w1);
    cvt8(&Bs[srow][skh + 8], w2, w3);
    __syncthreads();
    bf16x8 af[4], bfr[4];
#pragma unroll
    for (int i = 0; i < 4; ++i) af[i] = *(const bf16x8*)&As[wm * 64 + i * 16 + fr][fq * 8];
#pragma unroll
    for (int j = 0; j < 4; ++j) bfr[j] = *(const bf16x8*)&Bs[wn * 64 + j * 16 + fr][fq * 8];
#pragma unroll
    for (int i = 0; i < 4; ++i)
#pragma unroll
      for (int j = 0; j < 4; ++j)
        acc[i][j] = __builtin_amdgcn_mfma_f32_16x16x32_bf16(af[i], bfr[j], acc[i][j], 0, 0, 0);
    __syncthreads();
  }
#pragma unroll
  for (int i = 0; i < 4; ++i) {
    int mB = m0 + wm * 64 + i * 16 + fq * 4;
#pragma unroll
    for (int j = 0; j < 4; ++j) {
      int n = n0 + wn * 64 + j * 16 + fr;
      float bz = bias[n];
#pragma unroll
      for (int r2 = 0; r2 < 4; ++r2) {
        float v = acc[i][j][r2] + bz;
        if (relu) v = fmaxf(v, 0.f);
        C[(long)(mB + r2) * N + n] = v;
      }
    }
  }
}

// ---- bf16 MFMA embed: C[b,s,a] = sum_c X[b,c,s]*W[a,c] + bias + pe - sub ----
__global__ __launch_bounds__(256) void k_mfma_embed(
    const float* __restrict__ X,   // [B,1024,196]
    const float* __restrict__ W,   // [512,1024]
    const float* __restrict__ bias,
    const float* __restrict__ wemb, const float* __restrict__ hemb,
    const float* __restrict__ sub,  // nullptr or [BS,512]
    float* __restrict__ C) {        // [BS,512]
  __shared__ short As[128][40];
  __shared__ short Bs[128][40];
  const int tid = threadIdx.x;
  const int lane = tid & 63, wave = tid >> 6;
  const int wm = wave >> 1, wn = wave & 1;
  const int m0 = blockIdx.y * 128, n0 = blockIdx.x * 128;
  const int K = 1024, N = 512;
  const int srow = tid >> 1, skh = (tid & 1) * 16;
  const float* Wp = W + (long)(n0 + srow) * K + skh;
  const int arow = tid & 127, khalf = tid >> 7;
  const int am = m0 + arow;
  const int ab = am / 196, as_ = am % 196;
  const float* Xp = X + (long)ab * 200704 + as_;
  const int fr = lane & 15, fq = lane >> 4;
  f32x4 acc[4][4] = {};
  for (int k0 = 0; k0 < K; k0 += 32) {
#pragma unroll
    for (int i = 0; i < 16; ++i) {
      int kk = 2 * i + khalf;
      As[arow][kk] = f2bf(Xp[(long)(k0 + kk) * 196]);
    }
    float4 w0 = *(const float4*)(Wp + k0);
    float4 w1 = *(const float4*)(Wp + k0 + 4);
    float4 w2 = *(const float4*)(Wp + k0 + 8);
    float4 w3 = *(const float4*)(Wp + k0 + 12);
    cvt8(&Bs[srow][skh], w0, w1);
    cvt8(&Bs[srow][skh + 8], w2, w3);
    __syncthreads();
    bf16x8 af[4], bfr[4];
#pragma unroll
    for (int i = 0; i < 4; ++i) af[i] = *(const bf16x8*)&As[wm * 64 + i * 16 + fr][fq * 8];
#pragma unroll
    for (int j = 0; j < 4; ++j) bfr[j] = *(const bf16x8*)&Bs[wn * 64 + j * 16 + fr][fq * 8];
#pragma unroll
    for (int i = 0; i < 4; ++i)
#pragma unroll
      for (int j = 0; j < 4; ++j)
        acc[i][j] = __builtin_amdgcn_mfma_f32_16x16x32_bf16(af[i], bfr[j], acc[i][j], 0, 0, 0);
    __syncthreads();
  }
#pragma unroll
  for (int i = 0; i < 4; ++i) {
    int mB = m0 + wm * 64 + i * 16 + fq * 4;
#pragma unroll
    for (int j = 0; j < 4; ++j) {
      int n = n0 + wn * 64 + j * 16 + fr;
      float bz = bias[n];
#pragma unroll
      for (int r2 = 0; r2 < 4; ++r2) {
        int m = mB + r2;
        int s = m % 196;
        float pe = (n < 256) ? wemb[(s % 14) * 256 + n] : hemb[(s / 14) * 256 + (n - 256)];
        float v = acc[i][j][r2] + bz + pe;
        if (sub) v -= sub[(long)m * N + n];
        C[(long)m * N + n] = v;
      }
    }
  }
}

// ---- Batched bf16 MFMA NT: C[z][m,n] = scale*sum_k A[z][m,k]*B[z][n,k], opt clamp ----
// 64x64 tile, 4 waves (wave = n-frag). Row-clamped loads, bounded stores.
__global__ __launch_bounds__(256) void k_mfma_bnt(
    const float* __restrict__ A, const float* __restrict__ B, float* __restrict__ C,
    int M, int N, int K, int lda, int ldb, int ldc, int nz2,
    int64_t sA1, int64_t sA2, int64_t sB1, int64_t sB2, int64_t sC1, int64_t sC2,
    float scale, int clampf) {
  __shared__ short As[64][40];
  __shared__ short Bs[64][40];
  const int tid = threadIdx.x;
  const int lane = tid & 63, wave = tid >> 6;
  const int m0 = blockIdx.y * 64, n0 = blockIdx.x * 64;
  const int z = blockIdx.z, z1 = z / nz2, z2 = z % nz2;
  const float* Ab = A + z1 * sA1 + z2 * sA2;
  const float* Bb = B + z1 * sB1 + z2 * sB2;
  float* Cb = C + z1 * sC1 + z2 * sC2;
  const int sr = tid >> 2, skh = (tid & 3) * 8;
  const int ar = (m0 + sr < M) ? m0 + sr : M - 1;
  const int br = (n0 + sr < N) ? n0 + sr : N - 1;
  const float* Ap = Ab + (long)ar * lda + skh;
  const float* Bp = Bb + (long)br * ldb + skh;
  const int fr = lane & 15, fq = lane >> 4;
  f32x4 acc[4] = {};
  for (int k0 = 0; k0 < K; k0 += 32) {
    float4 a0 = *(const float4*)(Ap + k0);
    float4 a1 = *(const float4*)(Ap + k0 + 4);
    float4 b0 = *(const float4*)(Bp + k0);
    float4 b1 = *(const float4*)(Bp + k0 + 4);
    cvt8(&As[sr][skh], a0, a1);
    cvt8(&Bs[sr][skh], b0, b1);
    __syncthreads();
    bf16x8 bfr = *(const bf16x8*)&Bs[wave * 16 + fr][fq * 8];
#pragma unroll
    for (int i = 0; i < 4; ++i) {
      bf16x8 af = *(const bf16x8*)&As[i * 16 + fr][fq * 8];
      acc[i] = __builtin_amdgcn_mfma_f32_16x16x32_bf16(af, bfr, acc[i], 0, 0, 0);
    }
    __syncthreads();
  }
  const int n = n0 + wave * 16 + fr;
  if (n < N) {
#pragma unroll
    for (int i = 0; i < 4; ++i) {
      int mb = m0 + i * 16 + fq * 4;
#pragma unroll
      for (int r2 = 0; r2 < 4; ++r2) {
        int m = mb + r2;
        if (m < M) {
          float v = acc[i][r2] * scale;
          if (clampf) v = fminf(fmaxf(v, -100.f), 100.f);
          Cb[(long)m * ldc + n] = v;
        }
      }
    }
  }
}

// ---- Batched bf16 MFMA NN: C[z][m,n] = sum_k A[z][m,k]*B[z][k,n] ----
// A ld cols all valid (pads are zero); B k-rows clamped to KBvalid-1.
__global__ __launch_bounds__(256) void k_mfma_bnn(
    const float* __restrict__ A, const float* __restrict__ B, float* __restrict__ C,
    int M, int N, int K, int KBvalid, int lda, int ldb, int ldc, int nz2,
    int64_t sA1, int64_t sA2, int64_t sB1, int64_t sB2, int64_t sC1, int64_t sC2) {
  __shared__ short As[64][40];
  __shared__ short Bs[64][40];
  const int tid = threadIdx.x;
  const int lane = tid & 63, wave = tid >> 6;
  const int m0 = blockIdx.y * 64, n0 = blockIdx.x * 64;
  const int z = blockIdx.z, z1 = z / nz2, z2 = z % nz2;
  const float* Ab = A + z1 * sA1 + z2 * sA2;
  const float* Bb = B + z1 * sB1 + z2 * sB2;
  float* Cb = C + z1 * sC1 + z2 * sC2;
  const int sr = tid >> 2, skh = (tid & 3) * 8;
  const int ar = (m0 + sr < M) ? m0 + sr : M - 1;
  const float* Ap = Ab + (long)ar * lda + skh;
  const int bk = tid >> 3, bn = (tid & 7) * 8;   // B transposed staging
  const int fr = lane & 15, fq = lane >> 4;
  f32x4 acc[4] = {};
  for (int k0 = 0; k0 < K; k0 += 32) {
    float4 a0 = *(const float4*)(Ap + k0);
    float4 a1 = *(const float4*)(Ap + k0 + 4);
    cvt8(&As[sr][skh], a0, a1);
    int kc = k0 + bk;
    if (kc >= KBvalid) kc = KBvalid - 1;
    const float* bp = Bb + (long)kc * ldb + n0 + bn;
    float4 b0 = *(const float4*)(bp);
    float4 b1 = *(const float4*)(bp + 4);
    short tb[8];
    cvt8(tb, b0, b1);
#pragma unroll
    for (int j = 0; j < 8; ++j) Bs[bn + j][bk] = tb[j];
    __syncthreads();
    bf16x8 bfr = *(const bf16x8*)&Bs[wave * 16 + fr][fq * 8];
#pragma unroll
    for (int i = 0; i < 4; ++i) {
      bf16x8 af = *(const bf16x8*)&As[i * 16 + fr][fq * 8];
      acc[i] = __builtin_amdgcn_mfma_f32_16x16x32_bf16(af, bfr, acc[i], 0, 0, 0);
    }
    __syncthreads();
  }
  const int n = n0 + wave * 16 + fr;
  if (n < N) {
#pragma unroll
    for (int i = 0; i < 4; ++i) {
      int mb = m0 + i * 16 + fq * 4;
#pragma unroll
      for (int r2 = 0; r2 < 4; ++r2) {
        int m = mb + r2;
        if (m < M) Cb[(long)m * ldc + n] = acc[i][r2];
      }
    }
  }
}

// ---- MFMA correlation: C[i,j] += scale * sum_m Za[m,i]*Zb[m,j] (split-K atomic) ----
__global__ __launch_bounds__(256) void k_mfma_corr(
    const float* __restrict__ Za, const float* __restrict__ Zb,
    float* __restrict__ C, int mchunk, float scale) {
  __shared__ short As[64][40];
  __shared__ short Bs[64][40];
  const int tid = threadIdx.x;
  const int lane = tid & 63, wave = tid >> 6;
  const int i0 = blockIdx.y * 64, j0 = blockIdx.x * 64;
  const int mstart = blockIdx.z * mchunk;
  const int tm = tid >> 3, tcb = (tid & 7) * 8;
  const int fr = lane & 15, fq = lane >> 4;
  f32x4 acc[4] = {};
  for (int m0 = mstart; m0 < mstart + mchunk; m0 += 32) {
    const float* za = Za + (long)(m0 + tm) * 512;
    const float* zb = Zb + (long)(m0 + tm) * 512;
    float4 a0 = *(const float4*)(za + i0 + tcb);
    float4 a1 = *(const float4*)(za + i0 + tcb + 4);
    float4 b0 = *(const float4*)(zb + j0 + tcb);
    float4 b1 = *(const float4*)(zb + j0 + tcb + 4);
    short ta[8], tb[8];
    cvt8(ta, a0, a1);
    cvt8(tb, b0, b1);
#pragma unroll
    for (int j = 0; j < 8; ++j) { As[tcb + j][tm] = ta[j]; Bs[tcb + j][tm] = tb[j]; }
    __syncthreads();
    bf16x8 bfr = *(const bf16x8*)&Bs[wave * 16 + fr][fq * 8];
#pragma unroll
    for (int i = 0; i < 4; ++i) {
      bf16x8 af = *(const bf16x8*)&As[i * 16 + fr][fq * 8];
      acc[i] = __builtin_amdgcn_mfma_f32_16x16x32_bf16(af, bfr, acc[i], 0, 0, 0);
    }
    __syncthreads();
  }
  const int j = j0 + wave * 16 + fr;
#pragma unroll
  for (int i = 0; i < 4; ++i) {
    int ib = i0 + i * 16 + fq * 4;
#pragma unroll
    for (int r2 = 0; r2 < 4; ++r2)
      atomicAdd(&C[(long)(ib + r2) * 512 + j], acc[i][r2] * scale);
  }
}

// ---------------- fp32 GEMM fallback (small M) ----------------
__global__ __launch_bounds__(256) void k_gemm_nt(
    const float* __restrict__ A, const float* __restrict__ W,
    const float* __restrict__ bias, float* __restrict__ C,
    int M, int N, int K, int relu) {
  __shared__ float As[16][68];
  __shared__ float Ws[16][68];
  const int tx = threadIdx.x, ty = threadIdx.y;
  const int tid = ty * 16 + tx;
  const int m0 = blockIdx.y * 64, n0 = blockIdx.x * 64;
  const int lr = tid >> 2, lk = (tid & 3) << 2;
  const float* Ap = A + (long)(m0 + lr) * K + lk;
  const float* Wp = W + (long)(n0 + lr) * K + lk;
  float acc[4][4] = {};
  for (int k0 = 0; k0 < K; k0 += 16) {
    float4 av = *(const float4*)(Ap + k0);
    float4 wv = *(const float4*)(Wp + k0);
    As[lk + 0][lr] = av.x; As[lk + 1][lr] = av.y; As[lk + 2][lr] = av.z; As[lk + 3][lr] = av.w;
    Ws[lk + 0][lr] = wv.x; Ws[lk + 1][lr] = wv.y; Ws[lk + 2][lr] = wv.z; Ws[lk + 3][lr] = wv.w;
    __syncthreads();
#pragma unroll
    for (int kk = 0; kk < 16; ++kk) {
      float4 a4 = *(const float4*)&As[kk][ty * 4];
      float4 w4 = *(const float4*)&Ws[kk][tx * 4];
      float a[4] = {a4.x, a4.y, a4.z, a4.w};
      float w[4] = {w4.x, w4.y, w4.z, w4.w};
#pragma unroll
      for (int i = 0; i < 4; ++i)
#pragma unroll
        for (int j = 0; j < 4; ++j) acc[i][j] += a[i] * w[j];
    }
    __syncthreads();
  }
#pragma unroll
  for (int i = 0; i < 4; ++i) {
    int m = m0 + ty * 4 + i;
#pragma unroll
    for (int j = 0; j < 4; ++j) {
      int n = n0 + tx * 4 + j;
      float v = acc[i][j] + bias[n];
      if (relu) v = fmaxf(v, 0.f);
      C[(long)m * N + n] = v;
    }
  }
}

// ---- Row softmax over rows of width 196, ld=SLD(224); zeroes pad cols. 1 wave/row. ----
__global__ __launch_bounds__(256) void k_softmax_rows(float* __restrict__ S, int nrows) {
  int row = blockIdx.x * 4 + (threadIdx.x >> 6);
  int lane = threadIdx.x & 63;
  if (row >= nrows) return;
  float* p = S + (long)row * SLD;
  float v0 = p[lane];
  float v1 = p[lane + 64];
  float v2 = p[lane + 128];
  float v3 = (lane + 192 < 196) ? p[lane + 192] : -1e30f;
  float mx = fmaxf(fmaxf(v0, v1), fmaxf(v2, v3));
#pragma unroll
  for (int o = 32; o > 0; o >>= 1) mx = fmaxf(mx, __shfl_down(mx, o, 64));
  mx = __shfl(mx, 0, 64);
  float e0 = expf(v0 - mx), e1 = expf(v1 - mx), e2 = expf(v2 - mx);
  float e3 = (lane + 192 < 196) ? expf(v3 - mx) : 0.f;
  float s = e0 + e1 + e2 + e3;
#pragma unroll
  for (int o = 32; o > 0; o >>= 1) s += __shfl_down(s, o, 64);
  s = __shfl(s, 0, 64);
  float inv = 1.0f / s;
  p[lane] = e0 * inv;
  p[lane + 64] = e1 * inv;
  p[lane + 128] = e2 * inv;
  if (lane + 192 < SLD) p[lane + 192] = (lane + 192 < 196) ? e3 * inv : 0.f;
}

// ---- Residual + LayerNorm (in place into h) ----
__global__ __launch_bounds__(256) void k_addln(
    float* __restrict__ h, const float* __restrict__ o,
    const float* __restrict__ g, const float* __restrict__ be) {
  __shared__ float red[4];
  long row = blockIdx.x;
  float* hr = h + row * 512;
  const float* orow = o + row * 512;
  int t = threadIdx.x;
  float v0 = hr[t] + orow[t];
  float v1 = hr[t + 256] + orow[t + 256];
  float mean = block_red256(v0 + v1, red, false) * (1.0f / 512.0f);
  float d0 = v0 - mean, d1 = v1 - mean;
  float var = block_red256(d0 * d0 + d1 * d1, red, false) * (1.0f / 512.0f);
  float inv = 1.0f / sqrtf(var + 1e-5f);
  hr[t] = d0 * inv * g[t] + be[t];
  hr[t + 256] = d1 * inv * g[t + 256] + be[t + 256];
}

// ---- small utility kernels ----
__global__ void k_zero(float* __restrict__ p, int n) {
  int i = blockIdx.x * 256 + threadIdx.x;
  if (i < n) p[i] = 0.f;
}

__global__ __launch_bounds__(256) void k_colstats(
    const float* __restrict__ f, float* __restrict__ sums, float* __restrict__ sqs) {
  int c = blockIdx.x * 32 + (threadIdx.x & 31);
  int rbase = blockIdx.y * 256;
  int r0 = rbase + (threadIdx.x >> 5);
  float s = 0.f, s2 = 0.f;
  for (int r = r0; r < rbase + 256; r += 8) {
    float v = f[(long)r * 512 + c];
    s += v; s2 += v * v;
  }
  __shared__ float sh[256], sh2[256];
  sh[threadIdx.x] = s; sh2[threadIdx.x] = s2;
  __syncthreads();
  if (threadIdx.x < 32) {
    for (int i = 1; i < 8; ++i) { s += sh[i * 32 + threadIdx.x]; s2 += sh2[i * 32 + threadIdx.x]; }
    atomicAdd(&sums[c], s);
    atomicAdd(&sqs[c], s2);
  }
}

__global__ void k_finstats(const float* __restrict__ sums, const float* __restrict__ sqs,
                           float* __restrict__ mean, float* __restrict__ istd) {
  int c = blockIdx.x * 256 + threadIdx.x;
  float mu = sums[c] / 12544.0f;
  float var = (sqs[c] - 12544.0f * mu * mu) / 12543.0f;
  mean[c] = mu;
  istd[c] = 1.0f / sqrtf(var);
}

__global__ __launch_bounds__(256) void k_znorm(float* __restrict__ f, const float* __restrict__ mean,
                                               const float* __restrict__ istd) {
  long i = (long)blockIdx.x * 256 + threadIdx.x;
  int c = (int)(i & 511);
  f[i] = (f[i] - mean[c]) * istd[c];
}

// CDCR loss: 256-block partial reduce + final combine
__global__ __launch_bounds__(256) void k_cdcr_part(const float* __restrict__ Cm,
                                                   double* __restrict__ part) {
  int base = blockIdx.x * 1024;
  double on = 0, off = 0;
  for (int i = base + threadIdx.x; i < base + 1024; i += 256) {
    float v = Cm[i];
    int r = i >> 9, c = i & 511;
    if (r == c) { double d = (double)v - 1.0; on += d * d; }
    else        { off += (double)v * (double)v; }
  }
  __shared__ double s_on[256], s_off[256];
  s_on[threadIdx.x] = on; s_off[threadIdx.x] = off;
  __syncthreads();
  for (int st = 128; st > 0; st >>= 1) {
    if (threadIdx.x < st) { s_on[threadIdx.x] += s_on[threadIdx.x + st]; s_off[threadIdx.x] += s_off[threadIdx.x + st]; }
    __syncthreads();
  }
  if (threadIdx.x == 0) { part[blockIdx.x] = s_on[0]; part[256 + blockIdx.x] = s_off[0]; }
}

__global__ void k_cdcr_fin(const double* __restrict__ part, float* __restrict__ out) {
  __shared__ double s_on[256], s_off[256];
  s_on[threadIdx.x] = part[threadIdx.x];
  s_off[threadIdx.x] = part[256 + threadIdx.x];
  __syncthreads();
  for (int st = 128; st > 0; st >>= 1) {
    if (threadIdx.x < st) { s_on[threadIdx.x] += s_on[threadIdx.x + st]; s_off[threadIdx.x] += s_off[threadIdx.x + st]; }
    __syncthreads();
  }
  if (threadIdx.x == 0) out[0] = (float)(s_on[0] + 0.003 * s_off[0]);
}

__global__ __launch_bounds__(64) void k_mask(const float* __restrict__ capo, float* __restrict__ mask) {
  int pidx = blockIdx.x;
  float s = 0.f;
  for (int i = threadIdx.x; i < 512; i += 64) s += capo[(long)pidx * 512 + i];
#pragma unroll
  for (int o = 32; o > 0; o >>= 1) s += __shfl_down(s, o, 64);
  if (threadIdx.x == 0) mask[pidx] = (s != 0.f) ? 1.f : 0.f;
}

__global__ __launch_bounds__(256) void k_meannc(const float* __restrict__ src, const float* __restrict__ mask,
                                                float* __restrict__ vec) {
  int d = blockIdx.x * 256 + threadIdx.x;
  int b = blockIdx.y;
  float acc = 0.f, ms = 0.f;
  for (int nc = 0; nc < 16; ++nc) {
    float mk = mask ? mask[b * 16 + nc] : 1.f;
    acc += src[((long)b * 16 + nc) * 512 + d] * mk;
    ms += mk;
  }
  vec[(long)b * 512 + d] = acc / fmaxf(ms, 1e-6f);
}

__global__ __launch_bounds__(256) void k_mse(const float* __restrict__ full, const float* __restrict__ vec,
                                             double* __restrict__ part) {
  double loc = 0;
  const long n = NOUT;
  for (long i = (long)blockIdx.x * 256 + threadIdx.x; i < n; i += 256L * 1024) {
    int d = (int)(i & 511);
    int b = (int)(i >> 9) / 196;
    float df = full[i] - vec[b * 512 + d];
    loc += (double)df * (double)df;
  }
  __shared__ double sh[256];
  sh[threadIdx.x] = loc;
  __syncthreads();
  for (int st = 128; st > 0; st >>= 1) {
    if (threadIdx.x < st) sh[threadIdx.x] += sh[threadIdx.x + st];
    __syncthreads();
  }
  if (threadIdx.x == 0) part[blockIdx.x] = sh[0];
}

__global__ void k_finloss(const double* __restrict__ part, float* __restrict__ out) {
  __shared__ double sh[256];
  double s = 0;
  for (int i = threadIdx.x; i < 4096; i += 256) s += part[i];
  sh[threadIdx.x] = s;
  __syncthreads();
  for (int st = 128; st > 0; st >>= 1) {
    if (threadIdx.x < st) sh[threadIdx.x] += sh[threadIdx.x + st];
    __syncthreads();
  }
  if (threadIdx.x == 0) out[0] = (float)(sh[0] / (64.0 * 196.0 * 512.0));
}

__global__ __launch_bounds__(256) void k_concat2(float* __restrict__ dst, const float* __restrict__ a,
                                                 const float* __restrict__ b) {
  int i = blockIdx.x * 256 + threadIdx.x;   // 64*1024
  int col = i & 1023, row = i >> 10;
  dst[i] = (col < 512) ? a[row * 512 + col] : b[row * 512 + col - 512];
}

// comb chunk: rows [r0, r0+6272) of [BS,2048] into dst
__global__ __launch_bounds__(256) void k_comb_chunk(
    float* __restrict__ dst, const float* __restrict__ d1, const float* __restrict__ d2,
    const float* __restrict__ txt, const float* __restrict__ al, long r0) {
  long i = (long)blockIdx.x * 256 + threadIdx.x;  // 6272*2048
  int col = (int)(i & 2047);
  long m = r0 + (i >> 11);
  int b = (int)(m / 196);
  float v;
  if (col < 512)       v = d1[m * 512 + col];
  else if (col < 1024) v = d2[m * 512 + col - 512];
  else if (col < 1536) v = txt[(long)b * 512 + col - 1024];
  else                 v = al[(long)b * 512 + col - 1536];
  dst[i] = v;
}

// ---------------- host ----------------
extern "C" void kernel_launch(void* const* d_in, const int* in_sizes, int n_in,
                              void* d_out, int out_size, void* d_ws, size_t ws_size,
                              hipStream_t stream) {
  (void)in_sizes; (void)n_in; (void)out_size; (void)ws_size;
  const float* in1    = (const float*)d_in[0];
  const float* in2    = (const float*)d_in[1];
  const float* cap1   = (const float*)d_in[2];
  const float* cap2   = (const float*)d_in[3];
  const float* imgw   = (const float*)d_in[4];
  const float* imgb   = (const float*)d_in[5];
  const float* wemb   = (const float*)d_in[6];
  const float* hemb   = (const float*)d_in[7];
  const float* mlpw1  = (const float*)d_in[8];
  const float* mlpb1  = (const float*)d_in[9];
  const float* mlpw2  = (const float*)d_in[10];
  const float* mlpb2  = (const float*)d_in[11];
  const float* fcw    = (const float*)d_in[12];
  const float* fcb    = (const float*)d_in[13];
  const float* efcw   = (const float*)d_in[14];
  const float* efcb   = (const float*)d_in[15];
  const float* efc2w  = (const float*)d_in[16];
  const float* efc2b  = (const float*)d_in[17];
  const float* trinw  = (const float*)d_in[18];
  const float* trinb  = (const float*)d_in[19];
  const float* troutw = (const float*)d_in[20];
  const float* troutb = (const float*)d_in[21];
  const float* trlng  = (const float*)d_in[22];
  const float* trlnb  = (const float*)d_in[23];
  const float* itqw = (const float*)d_in[24]; const float* itqb = (const float*)d_in[25];
  const float* itkw = (const float*)d_in[26]; const float* itkb = (const float*)d_in[27];
  const float* itvw = (const float*)d_in[28]; const float* itvb = (const float*)d_in[29];
  const float* caqw = (const float*)d_in[30]; const float* caqb = (const float*)d_in[31];
  const float* cakw = (const float*)d_in[32]; const float* cakb = (const float*)d_in[33];
  const float* cavw = (const float*)d_in[34]; const float* cavb = (const float*)d_in[35];
  const float* saqw = (const float*)d_in[36]; const float* saqb = (const float*)d_in[37];
  const float* sakw = (const float*)d_in[38]; const float* sakb = (const float*)d_in[39];
  const float* savw = (const float*)d_in[40]; const float* savb = (const float*)d_in[41];

  float* out = (float*)d_out;

  // ---- workspace carve (~190 MB total) ----
  const size_t SZ = (size_t)BS * 512;        // 6,422,528 floats (24.5 MB)
  float* w = (float*)d_ws;
  auto alloc = [&](size_t n) { float* p = w; w += n; return p; };
  float* h1 = alloc(SZ);
  float* h2 = alloc(SZ);
  float* tA = alloc(SZ);
  float* tB = alloc(SZ);
  float* tC = alloc(SZ);
  float* tD = alloc(SZ);
  float* sbuf = alloc((size_t)128 * 196 * SLD);  // attention scores (22.5 MB)
  float* cap1o = alloc(64 * 16 * 512);
  float* cap2o = alloc(64 * 16 * 512);
  float* qc1   = alloc(64 * 16 * 512);
  float* qc2   = alloc(64 * 16 * 512);
  float* attb  = alloc(64 * 16 * 512);
  float* cmat  = alloc(512 * 512);
  float* colsum1 = alloc(512); float* colsq1 = alloc(512);
  float* colsum2 = alloc(512); float* colsq2 = alloc(512);
  float* mean1 = alloc(512); float* istd1 = alloc(512);
  float* mean2 = alloc(512); float* istd2 = alloc(512);
  float* mask1 = alloc(1024); float* mask2 = alloc(1024);
  float* vdbef = alloc(64 * 512); float* vdaft = alloc(64 * 512);
  float* vsbef = alloc(64 * 512); float* vsaft = alloc(64 * 512);
  float* cm1 = alloc(64 * 512); float* cm2 = alloc(64 * 512);
  float* vdyn = alloc(64 * 512); float* vsta = alloc(64 * 512);
  float* valign = alloc(64 * 512); float* vtxt = alloc(64 * 512);
  float* ccat = alloc(64 * 1024);
  double* msepart = (double*)alloc(4096 * 2);   // 4096 doubles
  double* cdcrpart = (double*)alloc(1024);      // 512 doubles

  auto gemm = [&](const float* Aa, const float* Ww, const float* bb, float* Cc,
                  int M, int N, int K, int relu) {
    if ((M % 128) == 0 && (N % 128) == 0 && (K % 32) == 0)
      k_mfma_nt<<<dim3(N / 128, M / 128), 256, 0, stream>>>(Aa, Ww, bb, Cc, M, N, K, relu);
    else
      k_gemm_nt<<<dim3(N / 64, (M + 63) / 64), dim3(16, 16), 0, stream>>>(Aa, Ww, bb, Cc, M, N, K, relu);
  };
  auto embed = [&](const float* X, const float* sub, float* Cc) {
    k_mfma_embed<<<dim3(4, BS / 128), 256, 0, stream>>>(X, imgw, imgb, wemb, hemb, sub, Cc);
  };
  const int64_t RB = (int64_t)SS * 512;   // 100352
  const int64_t QB = 16 * 512;            // 8192
  const int64_t ZS = (int64_t)196 * SLD;  // scores per (b,h)
  // GEMM-ized attention for D=512 single-head cases (ECA: M=196, ITDA: M=16)
  auto attn512 = [&](const float* Qp, const float* Kp, const float* Vp, float* Op,
                     int M, int64_t qZ, int64_t oZ, float scale) {
    int mt = (M + 63) / 64;
    int64_t sS = (int64_t)M * SLD;
    k_mfma_bnt<<<dim3(4, mt, 64), 256, 0, stream>>>(
        Qp, Kp, sbuf, M, 196, 512, 512, 512, SLD, 1,
        qZ, 0, RB, 0, sS, 0, scale, 1);
    k_softmax_rows<<<(64 * M + 3) / 4, 256, 0, stream>>>(sbuf, 64 * M);
    k_mfma_bnn<<<dim3(8, mt, 64), 256, 0, stream>>>(
        sbuf, Vp, Op, M, 512, SLD, 196, SLD, 512, 512, 1,
        sS, 0, RB, 0, oZ, 0);
  };
  // GEMM-ized MHA attention: D=64, H=8, chunked 16 batches at a time.
  auto attn_mha = [&](const float* Qp, const float* Kp, const float* Vp, float* Op) {
    for (int cb = 0; cb < 4; ++cb) {
      const float* Qb = Qp + (size_t)cb * 16 * RB;
      const float* Kb = Kp + (size_t)cb * 16 * RB;
      const float* Vb = Vp + (size_t)cb * 16 * RB;
      float* Ob = Op + (size_t)cb * 16 * RB;
      k_mfma_bnt<<<dim3(4, 4, 128), 256, 0, stream>>>(
          Qb, Kb, sbuf, 196, 196, 64, 512, 512, SLD, 8,
          RB, 64, RB, 64, ZS * 8, ZS, 0.125f, 0);
      k_softmax_rows<<<6272, 256, 0, stream>>>(sbuf, 25088);
      k_mfma_bnn<<<dim3(1, 4, 128), 256, 0, stream>>>(
          sbuf, Vb, Ob, 196, 64, SLD, 196, SLD, 512, 512, 8,
          ZS * 8, ZS, RB, 64, RB, 64);
    }
  };

  const float scalE = 1.0f / sqrtf(512.0f);

  // ---- Phase 1: embed (h starts as x) + caption projections ----
  embed(in1, nullptr, h1);
  embed(in2, nullptr, h2);
  gemm(cap1, fcw, fcb, cap1o, 1024, 512, 768, 0);
  gemm(cap2, fcw, fcb, cap2o, 1024, 512, 768, 0);
  k_meannc<<<dim3(2, 64), 256, 0, stream>>>(cap1o, nullptr, cm1);
  k_meannc<<<dim3(2, 64), 256, 0, stream>>>(cap2o, nullptr, cm2);

  // ---- Phase 2: CDCR loss (f1->tA, f2->tB, hidden chunk in tC..tD) ----
  for (int c = 0; c < 2; ++c) {
    const size_t off = (size_t)c * 6272 * 512;
    gemm(h1 + off, mlpw1, mlpb1, tC, 6272, 2048, 512, 1);
    gemm(tC, mlpw2, mlpb2, tA + off, 6272, 512, 2048, 0);
  }
  for (int c = 0; c < 2; ++c) {
    const size_t off = (size_t)c * 6272 * 512;
    gemm(h2 + off, mlpw1, mlpb1, tC, 6272, 2048, 512, 1);
    gemm(tC, mlpw2, mlpb2, tB + off, 6272, 512, 2048, 0);
  }
  k_zero<<<8, 256, 0, stream>>>(colsum1, 2048);  // colsum1..colsq2 contiguous
  k_colstats<<<dim3(16, 49), 256, 0, stream>>>(tA, colsum1, colsq1);
  k_colstats<<<dim3(16, 49), 256, 0, stream>>>(tB, colsum2, colsq2);
  k_finstats<<<2, 256, 0, stream>>>(colsum1, colsq1, mean1, istd1);
  k_finstats<<<2, 256, 0, stream>>>(colsum2, colsq2, mean2, istd2);
  k_znorm<<<25088, 256, 0, stream>>>(tA, mean1, istd1);
  k_znorm<<<25088, 256, 0, stream>>>(tB, mean2, istd2);
  k_zero<<<1024, 256, 0, stream>>>(cmat, 262144);
  k_mfma_corr<<<dim3(8, 8, 14), 256, 0, stream>>>(tA, tB, cmat, BS / 14, 1.0f / (float)BS);
  k_cdcr_part<<<256, 256, 0, stream>>>(cmat, cdcrpart);
  k_cdcr_fin<<<1, 256, 0, stream>>>(cdcrpart, out + NOUT);

  // ---- Phase 3: cross-transformer (2 layers, simultaneous update) ----
  for (int l = 0; l < 2; ++l) {
    const float* Wq = trinw + (size_t)l * 1536 * 512;
    const float* Wk = Wq + 512 * 512;
    const float* Wv = Wq + 2 * 512 * 512;
    const float* bq = trinb + l * 1536;
    const float* bk = bq + 512;
    const float* bv = bq + 1024;
    const float* Wo = troutw + (size_t)l * 512 * 512;
    const float* bo = troutb + l * 512;
    const float* g  = trlng + l * 512;
    const float* be = trlnb + l * 512;
    // dir1: q=h1, kv=h2
    gemm(h1, Wq, bq, tA, BS, 512, 512, 0);
    gemm(h2, Wk, bk, tB, BS, 512, 512, 0);
    gemm(h2, Wv, bv, tC, BS, 512, 512, 0);
    attn_mha(tA, tB, tC, tA);
    gemm(tA, Wo, bo, tD, BS, 512, 512, 0);       // o1 -> tD
    // dir2 projections from ORIGINAL h1,h2
    gemm(h2, Wq, bq, tA, BS, 512, 512, 0);
    gemm(h1, Wk, bk, tB, BS, 512, 512, 0);
    gemm(h1, Wv, bv, tC, BS, 512, 512, 0);
    k_addln<<<BS, 256, 0, stream>>>(h1, tD, g, be);  // h1 consumed above; update now
    attn_mha(tA, tB, tC, tA);
    gemm(tA, Wo, bo, tD, BS, 512, 512, 0);       // o2 -> tD
    k_addln<<<BS, 256, 0, stream>>>(h2, tD, g, be);
  }

  // ---- Phase 4: diffs via embed recompute (deterministic, bitwise-equal x) ----
  embed(in1, h1, tC);   // diff1 = x1 - h1
  embed(in2, h2, tD);   // diff2 = x2 - h2
  // h1, h2 now free

  // ---- Phase 5: ITDA (queries constant over S -> per-(b,nc) attention + masked mean) ----
  gemm(cap1o, itqw, itqb, qc1, 1024, 512, 512, 0);
  gemm(cap2o, itqw, itqb, qc2, 1024, 512, 512, 0);
  k_mask<<<1024, 64, 0, stream>>>(cap1o, mask1);
  k_mask<<<1024, 64, 0, stream>>>(cap2o, mask2);
  // K1,V1 from diff1
  gemm(tC, itkw, itkb, tA, BS, 512, 512, 0);
  gemm(tC, itvw, itvb, tB, BS, 512, 512, 0);
  attn512(qc2, tA, tB, attb, 16, QB, QB, scalE);
  k_meannc<<<dim3(2, 64), 256, 0, stream>>>(attb, mask2, vdbef);   // d_bef
  attn512(qc1, tA, tB, attb, 16, QB, QB, scalE);
  k_meannc<<<dim3(2, 64), 256, 0, stream>>>(attb, mask1, vsbef);   // s_bef
  // K2,V2 from diff2
  gemm(tD, itkw, itkb, tA, BS, 512, 512, 0);
  gemm(tD, itvw, itvb, tB, BS, 512, 512, 0);
  attn512(qc1, tA, tB, attb, 16, QB, QB, scalE);
  k_meannc<<<dim3(2, 64), 256, 0, stream>>>(attb, mask1, vdaft);   // d_aft
  attn512(qc2, tA, tB, attb, 16, QB, QB, scalE);
  k_meannc<<<dim3(2, 64), 256, 0, stream>>>(attb, mask2, vsaft);   // s_aft

  // ---- Phase 6: ECA x4 with immediate MSE vs ITDA vector ----
  auto eca_mse = [&](const float* xq, const float* xkv,
                     const float* qw2, const float* qb2, const float* kw2, const float* kb2,
                     const float* vw2, const float* vb2, const float* vec, double* part) {
    gemm(xq,  qw2, qb2, tA, BS, 512, 512, 0);
    gemm(xkv, kw2, kb2, tB, BS, 512, 512, 0);
    gemm(xkv, vw2, vb2, h1, BS, 512, 512, 0);
    attn512(tA, tB, h1, tA, 196, RB, RB, scalE);
    k_mse<<<1024, 256, 0, stream>>>(tA, vec, part);
  };
  eca_mse(tC, tD, caqw, caqb, cakw, cakb, cavw, cavb, vdbef, msepart);          // c12 vs d_bef
  eca_mse(tD, tC, caqw, caqb, cakw, cakb, cavw, cavb, vdaft, msepart + 1024);   // c21 vs d_aft
  eca_mse(tC, tC, saqw, saqb, sakw, sakb, savw, savb, vsbef, msepart + 2048);   // s11 vs s_bef
  eca_mse(tD, tD, saqw, saqb, sakw, sakb, savw, savb, vsaft, msepart + 3072);   // s22 vs s_aft
  k_finloss<<<1, 256, 0, stream>>>(msepart, out + NOUT + 1);

  // ---- Phase 7: efc chain (per-batch vectors, fp32 path M=64) ----
  k_concat2<<<256, 256, 0, stream>>>(ccat, vdbef, vdaft);
  gemm(ccat, efcw, efcb, vdyn, 64, 512, 1024, 1);
  k_concat2<<<256, 256, 0, stream>>>(ccat, vsbef, vsaft);
  gemm(ccat, efcw, efcb, vsta, 64, 512, 1024, 1);
  k_concat2<<<256, 256, 0, stream>>>(ccat, vdyn, vsta);
  gemm(ccat, efcw, efcb, valign, 64, 512, 1024, 1);
  k_concat2<<<256, 256, 0, stream>>>(ccat, cm1, cm2);
  gemm(ccat, efcw, efcb, vtxt, 64, 512, 1024, 1);

  // ---- Phase 8: final projection, chunked comb (6272 rows/chunk in tA..tB) ----
  for (int c = 0; c < 2; ++c) {
    long r0 = (long)c * 6272;
    k_comb_chunk<<<50176, 256, 0, stream>>>(tA, tC, tD, vtxt, valign, r0);
    gemm(tA, efc2w, efc2b, out + r0 * 512, 6272, 512, 2048, 1);
  }
}